// Round 7
// baseline (493.990 us; speedup 1.0000x reference)
//
#include <hip/hip_runtime.h>
#include <stdint.h>

typedef unsigned short u16;
typedef __attribute__((ext_vector_type(8))) short short8;
typedef __attribute__((ext_vector_type(4))) float floatx4;

#define MFMA16(a, b, c) __builtin_amdgcn_mfma_f32_16x16x32_bf16(a, b, c, 0, 0, 0)

static __device__ __forceinline__ void gl_lds16(const void* g, void* l) {
  __builtin_amdgcn_global_load_lds(
      (const __attribute__((address_space(1))) uint32_t*)g,
      (__attribute__((address_space(3))) uint32_t*)l, 16, 0, 0);
}

static __device__ __forceinline__ float b2f(u16 u) {
  union { float f; unsigned u; } v;
  v.u = ((unsigned)u) << 16;
  return v.f;
}
static __device__ __forceinline__ u16 f2b(float f) {
  union { float f; unsigned u; } v;
  v.f = f;
  unsigned r = v.u + 0x7fffu + ((v.u >> 16) & 1u);  // RNE
  return (u16)(r >> 16);
}
// Cheap round-half-up bf16 (2 VALU ops vs 5). Used ONLY for P in flash
// softmax (values in [0,1]; differs from RNE only on exact ties).
static __device__ __forceinline__ u16 f2b_rn(float f) {
  union { float f; unsigned u; } v;
  v.f = f;
  return (u16)((v.u + 0x8000u) >> 16);
}

// DPP row-rotate reductions over 16-lane groups (VALU, no LDS traffic).
template <int CTRL>
static __device__ __forceinline__ float dppf(float x) {
  return __builtin_bit_cast(
      float, __builtin_amdgcn_update_dpp(0, __builtin_bit_cast(int, x), CTRL,
                                         0xF, 0xF, true));
}
static __device__ __forceinline__ float sum16(float x) {
  x += dppf<0x128>(x);
  x += dppf<0x124>(x);
  x += dppf<0x122>(x);
  x += dppf<0x121>(x);
  return x;
}
static __device__ __forceinline__ float max16(float x) {
  x = fmaxf(x, dppf<0x128>(x));
  x = fmaxf(x, dppf<0x124>(x));
  x = fmaxf(x, dppf<0x122>(x));
  x = fmaxf(x, dppf<0x121>(x));
  return x;
}

// ---------------------------------------------------------------------------
// Input-dtype detector (f32 vs bf16).
// ---------------------------------------------------------------------------
__global__ __launch_bounds__(256) void detect_f32(const u16* __restrict__ x,
                                                  int* __restrict__ flag) {
  __shared__ int cnt[256];
  int c = 0;
  for (int i = threadIdx.x; i < 65536; i += 256) {
    int e = (x[i] >> 7) & 0xFF;
    if (e >= 140) ++c;
  }
  cnt[threadIdx.x] = c;
  __syncthreads();
  for (int s = 128; s > 0; s >>= 1) {
    if (threadIdx.x < (unsigned)s) cnt[threadIdx.x] += cnt[threadIdx.x + s];
    __syncthreads();
  }
  if (threadIdx.x == 0) *flag = (cnt[0] > 1000) ? 1 : 0;
}

// Vectorized flag-aware convert: 8 elems/thread.
__global__ __launch_bounds__(256) void convert_in8(const void* __restrict__ src,
                                                   u16* __restrict__ dst, int n8,
                                                   const int* __restrict__ flag) {
  int i = blockIdx.x * 256 + threadIdx.x;
  if (i >= n8) return;
  short8 r;
  if (*flag) {
    const float4* s = (const float4*)src;
    float4 a = s[2 * i], b = s[2 * i + 1];
    r[0] = (short)f2b(a.x); r[1] = (short)f2b(a.y);
    r[2] = (short)f2b(a.z); r[3] = (short)f2b(a.w);
    r[4] = (short)f2b(b.x); r[5] = (short)f2b(b.y);
    r[6] = (short)f2b(b.z); r[7] = (short)f2b(b.w);
  } else {
    r = ((const short8*)src)[i];
  }
  ((short8*)dst)[i] = r;
}

__global__ __launch_bounds__(256) void transpose_conv(const void* __restrict__ in,
                                                      u16* __restrict__ out,
                                                      int R, int Ccols,
                                                      const int* __restrict__ flag) {
  __shared__ u16 tile[32][33];
  int f = *flag;
  int c0 = blockIdx.x * 32, r0 = blockIdx.y * 32;
  int lx = threadIdx.x & 31, ly = threadIdx.x >> 5;
#pragma unroll
  for (int i = 0; i < 32; i += 8) {
    size_t idx = (size_t)(r0 + ly + i) * Ccols + c0 + lx;
    tile[ly + i][lx] = f ? f2b(((const float*)in)[idx]) : ((const u16*)in)[idx];
  }
  __syncthreads();
#pragma unroll
  for (int i = 0; i < 32; i += 8)
    out[(size_t)(c0 + ly + i) * R + r0 + lx] = tile[lx][ly + i];
}

// V half of KV [4096][4096] -> Vt[b][d][s]  ([2][2048][2048])
__global__ __launch_bounds__(256) void transpose_v(const u16* __restrict__ KV,
                                                   u16* __restrict__ Vt) {
  __shared__ u16 tile[32][33];
  int b = blockIdx.z;
  int d0 = blockIdx.x * 32, s0 = blockIdx.y * 32;
  int lx = threadIdx.x & 31, ly = threadIdx.x >> 5;
  const u16* src = KV + ((size_t)(b * 2048 + s0)) * 4096 + 2048 + d0;
#pragma unroll
  for (int i = 0; i < 32; i += 8)
    tile[ly + i][lx] = src[(size_t)(ly + i) * 4096 + lx];
  __syncthreads();
  u16* dst = Vt + ((size_t)(b * 2048 + d0)) * 2048 + s0;
#pragma unroll
  for (int i = 0; i < 32; i += 8)
    dst[(size_t)(ly + i) * 2048 + lx] = tile[lx][ly + i];
}

// ---------------------------------------------------------------------------
// 8-phase 256x256 NT GEMM (m201 template) — KV projection (grid 256).
// Phases split by (mh-half x kk): reads 8/8/4/4 ds_read_b128, 16 MFMA each.
// One half-tile (2 gl_lds) staged per phase; vmcnt(6) at tile top only.
// Invariant: a stage that clobbers a region issues only AFTER all ds_reads
// of that region (program order).
// ---------------------------------------------------------------------------
__global__ __launch_bounds__(512, 2) void gemm8(const u16* __restrict__ A,
                                                const u16* __restrict__ Bm,
                                                void* __restrict__ Cv,
                                                int M, int N, int K,
                                                const int* __restrict__ flag,
                                                int flag_mode) {
  __shared__ u16 Ash[2 * 256 * 64];
  __shared__ u16 Bsh[2 * 256 * 64];
  int tid = threadIdx.x, w = tid >> 6, lane = tid & 63;
  int quad = lane >> 4, l15 = lane & 15;
  int wr = w >> 2, wc = w & 3;
  int wm = wr * 128, wn = wc * 64;
  int m0 = blockIdx.y * 256, n0 = blockIdx.x * 256;
  int f32out = flag_mode ? *flag : 0;
  const int NT = K >> 6;

  int srow8 = lane >> 3;
  int gch = (lane & 7) ^ srow8;
  const u16* Ag = A + (size_t)(m0 + w * 8 + srow8) * K + gch * 8;
  const u16* Bg = Bm + (size_t)(n0 + w * 8 + srow8) * K + gch * 8;
  int ldsrow = w * 8;  // wave-uniform LDS row base; lane*16B added by HW

  floatx4 acc[8][4];
#pragma unroll
  for (int i = 0; i < 8; ++i)
#pragma unroll
    for (int j = 0; j < 4; ++j) acc[i][j] = floatx4{0.f, 0.f, 0.f, 0.f};

  int ch0 = ((quad ^ (l15 & 7)) << 3);        // kk=0 chunk byte-> u16 offset
  int ch1 = (((4 + quad) ^ (l15 & 7)) << 3);  // kk=1

  auto stage = [&](int qi) {
    int tau = qi >> 2;
    int tc = tau < NT ? tau : NT - 1;  // clamp keeps vmcnt counts exact
    int hh = qi & 3;                   // 0:B0 1:B1 2:A0 3:A1
    int half = (hh & 1) * 128;
    int sbuf = (tau & 1) * (256 * 64);
    size_t kof = (size_t)tc * 64;
    if (hh < 2) {
      gl_lds16(Bg + (size_t)half * K + kof,
               (void*)(Bsh + sbuf + (half + ldsrow) * 64));
      gl_lds16(Bg + (size_t)(half + 64) * K + kof,
               (void*)(Bsh + sbuf + (half + 64 + ldsrow) * 64));
    } else {
      gl_lds16(Ag + (size_t)half * K + kof,
               (void*)(Ash + sbuf + (half + ldsrow) * 64));
      gl_lds16(Ag + (size_t)(half + 64) * K + kof,
               (void*)(Ash + sbuf + (half + 64 + ldsrow) * 64));
    }
  };

  // Prologue: tile0 fully + 3 half-tiles of tile1 -> 3 half-tiles in flight.
  stage(0); stage(1); stage(2); stage(3);
  __asm__ volatile("s_waitcnt vmcnt(4)" ::: "memory");
  stage(4); stage(5); stage(6);
  __asm__ volatile("s_waitcnt vmcnt(6)" ::: "memory");
  __builtin_amdgcn_s_barrier();

  for (int t = 0; t < NT; ++t) {
    u16* As = Ash + (t & 1) * (256 * 64);
    u16* Bs = Bsh + (t & 1) * (256 * 64);
    if (t) {
      __asm__ volatile("s_waitcnt vmcnt(6)" ::: "memory");
      __builtin_amdgcn_s_barrier();
    }
    int qb = 7 + 4 * t;
    short8 bf[8], af0[8], af1[8];

    // ---- P0: read af0-kk0 + bf-kk0 (8 reads); MFMA mh0 x kk0 (16) ----
#pragma unroll
    for (int j = 0; j < 4; ++j) {
      int n = wn + 16 * j + l15;
      bf[2 * j] = *(const short8*)(Bs + n * 64 + ch0);
    }
#pragma unroll
    for (int i = 0; i < 4; ++i) {
      int m = wm + 16 * i + l15;
      af0[2 * i] = *(const short8*)(As + m * 64 + ch0);
    }
    stage(qb);
    __builtin_amdgcn_s_barrier();
    __asm__ volatile("s_waitcnt lgkmcnt(0)" ::: "memory");
    __builtin_amdgcn_sched_barrier(0);
    __builtin_amdgcn_s_setprio(1);
#pragma unroll
    for (int i = 0; i < 4; ++i)
#pragma unroll
      for (int j = 0; j < 4; ++j)
        acc[i][j] = MFMA16(af0[2 * i], bf[2 * j], acc[i][j]);
    __builtin_amdgcn_s_setprio(0);
    __builtin_amdgcn_s_barrier();

    // ---- P1: read af0-kk1 + bf-kk1 (8 reads); MFMA mh0 x kk1 (16) ----
#pragma unroll
    for (int j = 0; j < 4; ++j) {
      int n = wn + 16 * j + l15;
      bf[2 * j + 1] = *(const short8*)(Bs + n * 64 + ch1);
    }
#pragma unroll
    for (int i = 0; i < 4; ++i) {
      int m = wm + 16 * i + l15;
      af0[2 * i + 1] = *(const short8*)(As + m * 64 + ch1);
    }
    stage(qb + 1);
    __builtin_amdgcn_s_barrier();
    __asm__ volatile("s_waitcnt lgkmcnt(0)" ::: "memory");
    __builtin_amdgcn_sched_barrier(0);
    __builtin_amdgcn_s_setprio(1);
#pragma unroll
    for (int i = 0; i < 4; ++i)
#pragma unroll
      for (int j = 0; j < 4; ++j)
        acc[i][j] = MFMA16(af0[2 * i + 1], bf[2 * j + 1], acc[i][j]);
    __builtin_amdgcn_s_setprio(0);
    __builtin_amdgcn_s_barrier();

    // ---- P2: read af1-kk0 (4 reads); MFMA mh1 x kk0 (16) ----
#pragma unroll
    for (int i = 0; i < 4; ++i) {
      int m = wm + 64 + 16 * i + l15;
      af1[2 * i] = *(const short8*)(As + m * 64 + ch0);
    }
    stage(qb + 2);
    __builtin_amdgcn_s_barrier();
    __asm__ volatile("s_waitcnt lgkmcnt(0)" ::: "memory");
    __builtin_amdgcn_sched_barrier(0);
    __builtin_amdgcn_s_setprio(1);
#pragma unroll
    for (int i = 0; i < 4; ++i)
#pragma unroll
      for (int j = 0; j < 4; ++j)
        acc[4 + i][j] = MFMA16(af1[2 * i], bf[2 * j], acc[4 + i][j]);
    __builtin_amdgcn_s_setprio(0);
    __builtin_amdgcn_s_barrier();

    // ---- P3: read af1-kk1 (4 reads); MFMA mh1 x kk1 (16) ----
#pragma unroll
    for (int i = 0; i < 4; ++i) {
      int m = wm + 64 + 16 * i + l15;
      af1[2 * i + 1] = *(const short8*)(As + m * 64 + ch1);
    }
    stage(qb + 3);
    __builtin_amdgcn_s_barrier();
    __asm__ volatile("s_waitcnt lgkmcnt(0)" ::: "memory");
    __builtin_amdgcn_sched_barrier(0);
    __builtin_amdgcn_s_setprio(1);
#pragma unroll
    for (int i = 0; i < 4; ++i)
#pragma unroll
      for (int j = 0; j < 4; ++j)
        acc[4 + i][j] = MFMA16(af1[2 * i + 1], bf[2 * j + 1], acc[4 + i][j]);
    __builtin_amdgcn_s_setprio(0);
    __builtin_amdgcn_s_barrier();
  }

  // Epilogue (same C/D mapping as proven gemm_nt).
#pragma unroll
  for (int i = 0; i < 8; ++i)
#pragma unroll
    for (int r = 0; r < 4; ++r) {
      int row = m0 + wm + 16 * i + quad * 4 + r;
      if (f32out) {
        float* cp = (float*)Cv + (size_t)row * N + n0 + wn + l15;
#pragma unroll
        for (int j = 0; j < 4; ++j) cp[16 * j] = acc[i][j][r];
      } else {
        u16* cp = (u16*)Cv + (size_t)row * N + n0 + wn + l15;
#pragma unroll
        for (int j = 0; j < 4; ++j) cp[16 * j] = f2b(acc[i][j][r]);
      }
    }
}

// ---------------------------------------------------------------------------
// 8-phase 256x128 NT GEMM — Q and O projections. Grid (N/128, M/256) = 256
// blocks. 8 waves 2x4, per-wave 128x32 out (acc[8][2]). 3 stage-calls/K-tile
// (B@P1, A1'@P0, A0''@P3); vmcnt(4) at tile top only. LDS 96 KiB.
// ROUND-6 BUG FIX: A0 stage (clobbers rows 0..127 of current buffer, which
// wr=0 waves read as af1 at P3) moved from P2 to P3 AFTER the af1-kk1 reads —
// restores the stage-after-read invariant gemm8 maintains.
// ---------------------------------------------------------------------------
__global__ __launch_bounds__(512, 2) void gemm8n(const u16* __restrict__ A,
                                                 const u16* __restrict__ Bm,
                                                 void* __restrict__ Cv,
                                                 int M, int N, int K,
                                                 const int* __restrict__ flag,
                                                 int flag_mode) {
  __shared__ u16 Ash[2 * 256 * 64];
  __shared__ u16 Bsh[2 * 128 * 64];
  int tid = threadIdx.x, w = tid >> 6, lane = tid & 63;
  int quad = lane >> 4, l15 = lane & 15;
  int wr = w >> 2, wc = w & 3;
  int wm = wr * 128, wn = wc * 32;
  int m0 = blockIdx.y * 256, n0 = blockIdx.x * 128;
  int f32out = flag_mode ? *flag : 0;
  const int NT = K >> 6;

  int srow8 = lane >> 3;
  int gch = (lane & 7) ^ srow8;
  const u16* Ag = A + (size_t)(m0 + w * 8 + srow8) * K + gch * 8;
  const u16* Bg = Bm + (size_t)(n0 + w * 8 + srow8) * K + gch * 8;
  int ldsrow = w * 8;

  floatx4 acc[8][2];
#pragma unroll
  for (int i = 0; i < 8; ++i)
#pragma unroll
    for (int j = 0; j < 2; ++j) acc[i][j] = floatx4{0.f, 0.f, 0.f, 0.f};

  int ch0 = ((quad ^ (l15 & 7)) << 3);
  int ch1 = (((4 + quad) ^ (l15 & 7)) << 3);

  auto stage = [&](int qi) {
    int tau = qi / 3;
    int tc = tau < NT ? tau : NT - 1;
    int ss = qi - 3 * tau;  // 0:B 1:A0 2:A1
    size_t kof = (size_t)tc * 64;
    if (ss == 0) {
      int sB = (tau & 1) * (128 * 64);
      gl_lds16(Bg + kof, (void*)(Bsh + sB + ldsrow * 64));
      gl_lds16(Bg + (size_t)64 * K + kof,
               (void*)(Bsh + sB + (64 + ldsrow) * 64));
    } else {
      int sA = (tau & 1) * (256 * 64);
      int half = (ss - 1) * 128;
      gl_lds16(Ag + (size_t)half * K + kof,
               (void*)(Ash + sA + (half + ldsrow) * 64));
      gl_lds16(Ag + (size_t)(half + 64) * K + kof,
               (void*)(Ash + sA + (half + 64 + ldsrow) * 64));
    }
  };

  // Prologue: tile0 (6 loads) + 2 stage-calls of tile1 (4 loads).
  stage(0); stage(1); stage(2);
  stage(3); stage(4);
  __asm__ volatile("s_waitcnt vmcnt(4)" ::: "memory");
  __builtin_amdgcn_s_barrier();

  for (int t = 0; t < NT; ++t) {
    u16* As = Ash + (t & 1) * (256 * 64);
    u16* Bs = Bsh + (t & 1) * (128 * 64);
    if (t) {
      __asm__ volatile("s_waitcnt vmcnt(4)" ::: "memory");
      __builtin_amdgcn_s_barrier();
    }
    int qb = 5 + 3 * t;
    short8 bf[4], af0[8], af1[8];

    // ---- P0: read bf-kk0 (2) + af0-kk0 (4); stage tile t+1 A1 ----
#pragma unroll
    for (int j = 0; j < 2; ++j) {
      int n = wn + 16 * j + l15;
      bf[2 * j] = *(const short8*)(Bs + n * 64 + ch0);
    }
#pragma unroll
    for (int i = 0; i < 4; ++i) {
      int m = wm + 16 * i + l15;
      af0[2 * i] = *(const short8*)(As + m * 64 + ch0);
    }
    stage(qb);
    __builtin_amdgcn_s_barrier();
    __asm__ volatile("s_waitcnt lgkmcnt(0)" ::: "memory");
    __builtin_amdgcn_sched_barrier(0);
    __builtin_amdgcn_s_setprio(1);
#pragma unroll
    for (int i = 0; i < 4; ++i)
#pragma unroll
      for (int j = 0; j < 2; ++j)
        acc[i][j] = MFMA16(af0[2 * i], bf[2 * j], acc[i][j]);
    __builtin_amdgcn_s_setprio(0);
    __builtin_amdgcn_s_barrier();

    // ---- P1: read bf-kk1 (2) + af0-kk1 (4); stage tile t+2 B (after all
    // B reads of this tile have issued) ----
#pragma unroll
    for (int j = 0; j < 2; ++j) {
      int n = wn + 16 * j + l15;
      bf[2 * j + 1] = *(const short8*)(Bs + n * 64 + ch1);
    }
#pragma unroll
    for (int i = 0; i < 4; ++i) {
      int m = wm + 16 * i + l15;
      af0[2 * i + 1] = *(const short8*)(As + m * 64 + ch1);
    }
    stage(qb + 1);
    __builtin_amdgcn_s_barrier();
    __asm__ volatile("s_waitcnt lgkmcnt(0)" ::: "memory");
    __builtin_amdgcn_sched_barrier(0);
    __builtin_amdgcn_s_setprio(1);
#pragma unroll
    for (int i = 0; i < 4; ++i)
#pragma unroll
      for (int j = 0; j < 2; ++j)
        acc[i][j] = MFMA16(af0[2 * i + 1], bf[2 * j + 1], acc[i][j]);
    __builtin_amdgcn_s_setprio(0);
    __builtin_amdgcn_s_barrier();

    // ---- P2: read af1-kk0 (4); NO stage ----
#pragma unroll
    for (int i = 0; i < 4; ++i) {
      int m = wm + 64 + 16 * i + l15;
      af1[2 * i] = *(const short8*)(As + m * 64 + ch0);
    }
    __builtin_amdgcn_s_barrier();
    __asm__ volatile("s_waitcnt lgkmcnt(0)" ::: "memory");
    __builtin_amdgcn_sched_barrier(0);
    __builtin_amdgcn_s_setprio(1);
#pragma unroll
    for (int i = 0; i < 4; ++i)
#pragma unroll
      for (int j = 0; j < 2; ++j)
        acc[4 + i][j] = MFMA16(af1[2 * i], bf[2 * j], acc[4 + i][j]);
    __builtin_amdgcn_s_setprio(0);
    __builtin_amdgcn_s_barrier();

    // ---- P3: read af1-kk1 (4); stage tile t+2 A0 AFTER the reads (fix) ----
#pragma unroll
    for (int i = 0; i < 4; ++i) {
      int m = wm + 64 + 16 * i + l15;
      af1[2 * i + 1] = *(const short8*)(As + m * 64 + ch1);
    }
    stage(qb + 2);
    __builtin_amdgcn_s_barrier();
    __asm__ volatile("s_waitcnt lgkmcnt(0)" ::: "memory");
    __builtin_amdgcn_sched_barrier(0);
    __builtin_amdgcn_s_setprio(1);
#pragma unroll
    for (int i = 0; i < 4; ++i)
#pragma unroll
      for (int j = 0; j < 2; ++j)
        acc[4 + i][j] = MFMA16(af1[2 * i + 1], bf[2 * j + 1], acc[4 + i][j]);
    __builtin_amdgcn_s_setprio(0);
    __builtin_amdgcn_s_barrier();
  }

#pragma unroll
  for (int i = 0; i < 8; ++i)
#pragma unroll
    for (int r = 0; r < 4; ++r) {
      int row = m0 + wm + 16 * i + quad * 4 + r;
      if (f32out) {
        float* cp = (float*)Cv + (size_t)row * N + n0 + wn + l15;
#pragma unroll
        for (int j = 0; j < 2; ++j) cp[16 * j] = acc[i][j][r];
      } else {
        u16* cp = (u16*)Cv + (size_t)row * N + n0 + wn + l15;
#pragma unroll
        for (int j = 0; j < 2; ++j) cp[16 * j] = f2b(acc[i][j][r]);
      }
    }
}

// ---------------------------------------------------------------------------
// RoPE in-place; Q additionally scaled by 1/sqrt(dh) (folded from attention).
// ---------------------------------------------------------------------------
__global__ __launch_bounds__(256) void rope_kernel(u16* __restrict__ Q,
                                                   u16* __restrict__ KV) {
  const float scale = 0.08838834764831845f;  // 1/sqrt(128)
  int idx = blockIdx.x * 256 + threadIdx.x;
  int tok = idx >> 10;
  int rem = idx & 1023;
  int h = rem >> 6, i = rem & 63;
  int pos = tok & 2047;
  float f = __powf(10000.0f, -(float)(2 * i) * (1.0f / 128.0f));
  float ang = (float)pos * f;
  float s, c;
  sincosf(ang, &s, &c);

  size_t qb = (size_t)tok * 2048 + h * 128 + i;
  float q1 = b2f(Q[qb]), q2 = b2f(Q[qb + 64]);
  Q[qb] = f2b((q1 * c - q2 * s) * scale);
  Q[qb + 64] = f2b((q2 * c + q1 * s) * scale);

  size_t kb = (size_t)tok * 4096 + h * 128 + i;
  float k1 = b2f(KV[kb]), k2 = b2f(KV[kb + 64]);
  KV[kb] = f2b(k1 * c - k2 * s);
  KV[kb + 64] = f2b(k2 * c + k1 * s);
}

// ---------------------------------------------------------------------------
// Flash attention v8: round-4 best structure (256 pair-blocks, dbuf K/V
// staging) + VALU diet: (a) defer-rescale — skip o*=alv when all al==1
// exactly (bit-exact: multiply-by-1.0 is identity); (b) 2-op round-half-up
// for P-store bf16 conversion (was 5-op RNE).
// ---------------------------------------------------------------------------
__global__ __launch_bounds__(512, 1) void flash_attn(const u16* __restrict__ Q,
                                                     const u16* __restrict__ KV,
                                                     const u16* __restrict__ Vt,
                                                     u16* __restrict__ O) {
  const int S = 2048, D = 2048, KVld = 4096;
  int bh = blockIdx.x;    // 0..31
  int pair = blockIdx.y;  // 0..7
  int b = bh >> 4, h = bh & 15;
  int tid = threadIdx.x, w = tid >> 6, lane = tid & 63;
  int quad = lane >> 4, l15 = lane & 15;

  const u16* Qb = Q + (size_t)(b * S) * D + h * 128;
  const u16* Kb = KV + (size_t)(b * S) * KVld + h * 128;
  const u16* Vtb = Vt + ((size_t)(b * 2048 + h * 128)) * S;

  __shared__ u16 Ksh[2][64 * 128];  // [buf][krow][d], chunk ^= krow&7
  __shared__ u16 Vsh[2][128 * 64];  // [buf][d][k],   chunk ^= d&7
  __shared__ u16 Psh[8][16 * 64];   // per-wave P

  auto stage_kv = [&](int kt, int buf) {
    int kb = kt * 64;
#pragma unroll
    for (int tt = 0; tt < 2; ++tt) {
      int r0 = w * 8 + tt * 4;
      int row = r0 + quad;
      int g = (l15 & 8) | ((l15 & 7) ^ (row & 7));
      gl_lds16(Kb + (size_t)(kb + row) * KVld + g * 8,
               (void*)(Ksh[buf] + r0 * 128));
    }
#pragma unroll
    for (int tt = 0; tt < 2; ++tt) {
      int d0 = w * 16 + tt * 8;
      int d = d0 + (lane >> 3);
      int g = (lane & 7) ^ (d & 7);
      gl_lds16(Vtb + (size_t)d * S + kb + g * 8, (void*)(Vsh[buf] + d0 * 64));
    }
  };

  for (int pi = 0; pi < 2; ++pi) {
    int qt = pi ? (15 - pair) : pair;
    int qw = qt * 128 + w * 16;  // this wave's 16 q-rows

    short8 qf[4];
    {
      const u16* qp = Qb + (size_t)(qw + l15) * D + quad * 8;
#pragma unroll
      for (int kk = 0; kk < 4; ++kk) qf[kk] = *(const short8*)(qp + kk * 32);
    }

    floatx4 o[8];
#pragma unroll
    for (int t = 0; t < 8; ++t) o[t] = floatx4{0.f, 0.f, 0.f, 0.f};
    float mrow[4], lrow[4];
#pragma unroll
    for (int r = 0; r < 4; ++r) { mrow[r] = -1e30f; lrow[r] = 0.f; }

    int nk = 2 * qt + 2;
    stage_kv(0, 0);
    __syncthreads();

    for (int kt = 0; kt < nk; ++kt) {
      int kb = kt * 64;
      int cur = kt & 1;
      if (kt + 1 < nk) stage_kv(kt + 1, cur ^ 1);

      if (kb <= qw + 15) {  // wave has at least one unmasked row
        const u16* Kc = Ksh[cur];
        const u16* Vc = Vsh[cur];
        // --- QK^T: 4n x 4ksteps = 16 MFMA ---
        floatx4 sc[4];
#pragma unroll
        for (int nf = 0; nf < 4; ++nf) sc[nf] = floatx4{0.f, 0.f, 0.f, 0.f};
#pragma unroll
        for (int kk = 0; kk < 4; ++kk) {
          int c = kk * 4 + quad;
          short8 kf[4];
#pragma unroll
          for (int nf = 0; nf < 4; ++nf) {
            int n = nf * 16 + l15;
            int pc = (c & 8) | ((c & 7) ^ (n & 7));
            kf[nf] = *(const short8*)(Kc + n * 128 + pc * 8);
          }
#pragma unroll
          for (int nf = 0; nf < 4; ++nf) sc[nf] = MFMA16(qf[kk], kf[nf], sc[nf]);
        }

        // --- online softmax (1/sqrt(dh) pre-folded into Q) ---
        bool masked = (kb + 63 > qw);
        floatx4 alv;
#pragma unroll
        for (int r = 0; r < 4; ++r) {
          int qg = qw + quad * 4 + r;
          float v0 = sc[0][r], v1 = sc[1][r];
          float v2 = sc[2][r], v3 = sc[3][r];
          if (masked) {
            v0 = (kb + l15 <= qg) ? v0 : -1e30f;
            v1 = (kb + 16 + l15 <= qg) ? v1 : -1e30f;
            v2 = (kb + 32 + l15 <= qg) ? v2 : -1e30f;
            v3 = (kb + 48 + l15 <= qg) ? v3 : -1e30f;
          }
          float mx = max16(fmaxf(fmaxf(v0, v1), fmaxf(v2, v3)));
          float mn = fmaxf(mrow[r], mx);
          float al = __expf(mrow[r] - mn);
          mrow[r] = mn;
          float p0 = __expf(v0 - mn), p1 = __expf(v1 - mn);
          float p2 = __expf(v2 - mn), p3 = __expf(v3 - mn);
          float rs = sum16((p0 + p1) + (p2 + p3));
          lrow[r] = lrow[r] * al + rs;
          alv[r] = al;
          int m_ = quad * 4 + r;
          int sw = (m_ & 3) ^ ((m_ >> 2) << 1);
          int cb = l15 >> 3, e = l15 & 7;
          u16* pr = Psh[w] + m_ * 64;
          pr[(((0 + cb) ^ sw) << 3) + e] = f2b_rn(p0);
          pr[(((2 + cb) ^ sw) << 3) + e] = f2b_rn(p1);
          pr[(((4 + cb) ^ sw) << 3) + e] = f2b_rn(p2);
          pr[(((6 + cb) ^ sw) << 3) + e] = f2b_rn(p3);
        }
        // defer-rescale: al==1.0 exactly when the running max didn't grow.
        if (__any((alv[0] != 1.f) || (alv[1] != 1.f) ||
                  (alv[2] != 1.f) || (alv[3] != 1.f))) {
#pragma unroll
          for (int t = 0; t < 8; ++t) o[t] *= alv;
        }
        __asm__ volatile("s_waitcnt lgkmcnt(0)" ::: "memory");

        // --- PV: 8d x 2ksteps = 16 MFMA ---
#pragma unroll
        for (int ks = 0; ks < 2; ++ks) {
          int c = ks * 4 + quad;
          int psw = (l15 & 3) ^ ((l15 >> 2) << 1);
          short8 pf = *(const short8*)(Psh[w] + l15 * 64 + ((c ^ psw) << 3));
#pragma unroll
          for (int t = 0; t < 8; ++t) {
            int d = t * 16 + l15;
            short8 vf = *(const short8*)(Vc + d * 64 + ((c ^ (d & 7)) << 3));
            o[t] = MFMA16(pf, vf, o[t]);
          }
        }
      }
      __syncthreads();
    }

    // epilogue
#pragma unroll
    for (int r = 0; r < 4; ++r) {
      float inv = 1.0f / lrow[r];
      int qg = qw + quad * 4 + r;
      u16* op = O + (size_t)(b * S + qg) * D + h * 128;
#pragma unroll
      for (int t = 0; t < 8; ++t) op[t * 16 + l15] = f2b(o[t][r] * inv);
    }
  }
}

// ---------------------------------------------------------------------------
// Launch. ws (u16 after 64-elem flag pad):
//   xb 8.4M | Wbuf 8.4M (wq -> wkvT -> Vt -> wo) | Qb 8.4M | KVb 16.8M
//   AO aliases xb. Total ~84 MB.
// ---------------------------------------------------------------------------
extern "C" void kernel_launch(void* const* d_in, const int* in_sizes, int n_in,
                              void* d_out, int out_size, void* d_ws, size_t ws_size,
                              hipStream_t stream) {
  const void* x = d_in[0];
  const void* wq = d_in[1];
  const void* wkv = d_in[2];
  const void* wo = d_in[3];

  int* flag = (int*)d_ws;
  u16* xb = (u16*)d_ws + 64;
  u16* Wbuf = xb + (size_t)8388608;
  u16* Qb = Wbuf + (size_t)8388608;
  u16* KVb = Qb + (size_t)8388608;
  u16* AO = xb;  // x dead after KV projection

  detect_f32<<<1, 256, 0, stream>>>((const u16*)x, flag);
  convert_in8<<<4096, 256, 0, stream>>>(x, xb, 1048576, flag);
  convert_in8<<<2048, 256, 0, stream>>>(wq, Wbuf, 524288, flag);
  gemm8n<<<dim3(16, 16), 512, 0, stream>>>(xb, Wbuf, Qb, 4096, 2048, 2048, flag, 0);
  transpose_conv<<<dim3(128, 64), 256, 0, stream>>>(wkv, Wbuf, 2048, 4096, flag);
  gemm8<<<dim3(16, 16), 512, 0, stream>>>(xb, Wbuf, KVb, 4096, 4096, 2048, flag, 0);
  transpose_v<<<dim3(64, 64, 2), 256, 0, stream>>>(KVb, Wbuf);  // Wbuf := Vt
  rope_kernel<<<16384, 256, 0, stream>>>(Qb, KVb);
  flash_attn<<<dim3(32, 8), 512, 0, stream>>>(Qb, KVb, Wbuf, AO);
  convert_in8<<<2048, 256, 0, stream>>>(wo, Wbuf, 524288, flag);
  gemm8n<<<dim3(16, 16), 512, 0, stream>>>(AO, Wbuf, d_out, 4096, 2048, 2048, flag, 1);
}

// Round 8
// 418.732 us; speedup vs baseline: 1.1797x; 1.1797x over previous
//
#include <hip/hip_runtime.h>
#include <stdint.h>

typedef unsigned short u16;
typedef __attribute__((ext_vector_type(8))) short short8;
typedef __attribute__((ext_vector_type(4))) float floatx4;

#define MFMA16(a, b, c) __builtin_amdgcn_mfma_f32_16x16x32_bf16(a, b, c, 0, 0, 0)

static __device__ __forceinline__ void gl_lds16(const void* g, void* l) {
  __builtin_amdgcn_global_load_lds(
      (const __attribute__((address_space(1))) uint32_t*)g,
      (__attribute__((address_space(3))) uint32_t*)l, 16, 0, 0);
}

static __device__ __forceinline__ float b2f(u16 u) {
  union { float f; unsigned u; } v;
  v.u = ((unsigned)u) << 16;
  return v.f;
}
static __device__ __forceinline__ u16 f2b(float f) {
  union { float f; unsigned u; } v;
  v.f = f;
  unsigned r = v.u + 0x7fffu + ((v.u >> 16) & 1u);  // RNE
  return (u16)(r >> 16);
}
// Cheap round-half-up bf16 (2 VALU ops). P-store only (values in [0,1]).
static __device__ __forceinline__ u16 f2b_rn(float f) {
  union { float f; unsigned u; } v;
  v.f = f;
  return (u16)((v.u + 0x8000u) >> 16);
}

// DPP row-rotate reductions over 16-lane groups (VALU, no LDS traffic).
template <int CTRL>
static __device__ __forceinline__ float dppf(float x) {
  return __builtin_bit_cast(
      float, __builtin_amdgcn_update_dpp(0, __builtin_bit_cast(int, x), CTRL,
                                         0xF, 0xF, true));
}
static __device__ __forceinline__ float sum16(float x) {
  x += dppf<0x128>(x);
  x += dppf<0x124>(x);
  x += dppf<0x122>(x);
  x += dppf<0x121>(x);
  return x;
}
static __device__ __forceinline__ float max16(float x) {
  x = fmaxf(x, dppf<0x128>(x));
  x = fmaxf(x, dppf<0x124>(x));
  x = fmaxf(x, dppf<0x122>(x));
  x = fmaxf(x, dppf<0x121>(x));
  return x;
}

// ---------------------------------------------------------------------------
// Input-dtype detector, PARALLEL (round 8): was 1 block x 256 serial scalar
// loads = 10-30us latency-bound stall gating the whole pipeline. Now 32
// blocks x short8 vector loads + block reduce + device atomicAdd into a
// pre-zeroed counter. Consumers test (*flag > 1000).
// ---------------------------------------------------------------------------
__global__ __launch_bounds__(256) void detect_f32(const u16* __restrict__ x,
                                                  int* __restrict__ flag) {
  __shared__ int cnt[256];
  int i = blockIdx.x * 256 + threadIdx.x;  // 8192 threads x 8 u16 = 64K u16
  short8 v = ((const short8*)x)[i];
  int c = 0;
#pragma unroll
  for (int j = 0; j < 8; ++j) {
    int e = (((unsigned short)v[j]) >> 7) & 0xFF;
    c += (e >= 140) ? 1 : 0;
  }
  cnt[threadIdx.x] = c;
  __syncthreads();
  for (int s = 128; s > 0; s >>= 1) {
    if (threadIdx.x < (unsigned)s) cnt[threadIdx.x] += cnt[threadIdx.x + s];
    __syncthreads();
  }
  if (threadIdx.x == 0) atomicAdd(flag, cnt[0]);
}

// Vectorized flag-aware convert: 8 elems/thread.
__global__ __launch_bounds__(256) void convert_in8(const void* __restrict__ src,
                                                   u16* __restrict__ dst, int n8,
                                                   const int* __restrict__ flag) {
  int i = blockIdx.x * 256 + threadIdx.x;
  if (i >= n8) return;
  short8 r;
  if (*flag > 1000) {
    const float4* s = (const float4*)src;
    float4 a = s[2 * i], b = s[2 * i + 1];
    r[0] = (short)f2b(a.x); r[1] = (short)f2b(a.y);
    r[2] = (short)f2b(a.z); r[3] = (short)f2b(a.w);
    r[4] = (short)f2b(b.x); r[5] = (short)f2b(b.y);
    r[6] = (short)f2b(b.z); r[7] = (short)f2b(b.w);
  } else {
    r = ((const short8*)src)[i];
  }
  ((short8*)dst)[i] = r;
}

__global__ __launch_bounds__(256) void transpose_conv(const void* __restrict__ in,
                                                      u16* __restrict__ out,
                                                      int R, int Ccols,
                                                      const int* __restrict__ flag) {
  __shared__ u16 tile[32][33];
  int f = (*flag > 1000) ? 1 : 0;
  int c0 = blockIdx.x * 32, r0 = blockIdx.y * 32;
  int lx = threadIdx.x & 31, ly = threadIdx.x >> 5;
#pragma unroll
  for (int i = 0; i < 32; i += 8) {
    size_t idx = (size_t)(r0 + ly + i) * Ccols + c0 + lx;
    tile[ly + i][lx] = f ? f2b(((const float*)in)[idx]) : ((const u16*)in)[idx];
  }
  __syncthreads();
#pragma unroll
  for (int i = 0; i < 32; i += 8)
    out[(size_t)(c0 + ly + i) * R + r0 + lx] = tile[lx][ly + i];
}

// V half of KV [4096][4096] -> Vt[b][d][s]  ([2][2048][2048])
__global__ __launch_bounds__(256) void transpose_v(const u16* __restrict__ KV,
                                                   u16* __restrict__ Vt) {
  __shared__ u16 tile[32][33];
  int b = blockIdx.z;
  int d0 = blockIdx.x * 32, s0 = blockIdx.y * 32;
  int lx = threadIdx.x & 31, ly = threadIdx.x >> 5;
  const u16* src = KV + ((size_t)(b * 2048 + s0)) * 4096 + 2048 + d0;
#pragma unroll
  for (int i = 0; i < 32; i += 8)
    tile[ly + i][lx] = src[(size_t)(ly + i) * 4096 + lx];
  __syncthreads();
  u16* dst = Vt + ((size_t)(b * 2048 + d0)) * 2048 + s0;
#pragma unroll
  for (int i = 0; i < 32; i += 8)
    dst[(size_t)(ly + i) * 2048 + lx] = tile[lx][ly + i];
}

// ---------------------------------------------------------------------------
// NT GEMM (m97 structure, proven round 2) — Q and O projections. RESTORED in
// round 8: gemm8n (256x128 8-phase) was ~8us/dispatch SLOWER (8-MFMA phases
// too short to amortize barrier cadence).
// ---------------------------------------------------------------------------
__global__ __launch_bounds__(256) void gemm_nt(const u16* __restrict__ A,
                                               const u16* __restrict__ Bm,
                                               void* __restrict__ Cv,
                                               int M, int N, int K,
                                               const int* __restrict__ flag,
                                               int flag_mode) {
  __shared__ u16 Ash[128 * 64];
  __shared__ u16 Bsh[128 * 64];
  int tid = threadIdx.x, w = tid >> 6, lane = tid & 63;
  int quad = lane >> 4, l15 = lane & 15;
  int m0 = blockIdx.y * 128, n0 = blockIdx.x * 128;
  int wm = (w & 1) * 64, wn = (w >> 1) * 64;
  int f32out = flag_mode ? (*flag > 1000) : 0;

  floatx4 acc[4][4];
#pragma unroll
  for (int i = 0; i < 4; ++i)
#pragma unroll
    for (int j = 0; j < 4; ++j) acc[i][j] = floatx4{0.f, 0.f, 0.f, 0.f};

  int srow = lane >> 3;
  int gch = (lane & 7) ^ srow;
  const u16* Ag = A + (size_t)(m0 + w * 32 + srow) * K + gch * 8;
  const u16* Bg = Bm + (size_t)(n0 + w * 32 + srow) * K + gch * 8;

  for (int k0 = 0; k0 < K; k0 += 64) {
    __syncthreads();
#pragma unroll
    for (int t = 0; t < 4; ++t) {
      gl_lds16(Ag + (size_t)t * 8 * K + k0, (void*)(Ash + (w * 32 + t * 8) * 64));
      gl_lds16(Bg + (size_t)t * 8 * K + k0, (void*)(Bsh + (w * 32 + t * 8) * 64));
    }
    __syncthreads();
#pragma unroll
    for (int kk = 0; kk < 2; ++kk) {
      int c = kk * 4 + quad;
      short8 af[4], bf[4];
#pragma unroll
      for (int i = 0; i < 4; ++i) {
        int m = wm + 16 * i + l15;
        af[i] = *(const short8*)(Ash + m * 64 + ((c ^ (m & 7)) << 3));
        int n = wn + 16 * i + l15;
        bf[i] = *(const short8*)(Bsh + n * 64 + ((c ^ (n & 7)) << 3));
      }
#pragma unroll
      for (int i = 0; i < 4; ++i)
#pragma unroll
        for (int j = 0; j < 4; ++j) acc[i][j] = MFMA16(af[i], bf[j], acc[i][j]);
    }
  }

#pragma unroll
  for (int i = 0; i < 4; ++i)
#pragma unroll
    for (int r = 0; r < 4; ++r) {
      int row = m0 + wm + 16 * i + quad * 4 + r;
      if (f32out) {
        float* cp = (float*)Cv + (size_t)row * N + n0 + wn + l15;
#pragma unroll
        for (int j = 0; j < 4; ++j) cp[16 * j] = acc[i][j][r];
      } else {
        u16* cp = (u16*)Cv + (size_t)row * N + n0 + wn + l15;
#pragma unroll
        for (int j = 0; j < 4; ++j) cp[16 * j] = f2b(acc[i][j][r]);
      }
    }
}

// ---------------------------------------------------------------------------
// 8-phase 256x256 NT GEMM (m201 template) — KV projection (grid 256, proven
// rounds 3-7). Stage-after-read invariant throughout.
// ---------------------------------------------------------------------------
__global__ __launch_bounds__(512, 2) void gemm8(const u16* __restrict__ A,
                                                const u16* __restrict__ Bm,
                                                void* __restrict__ Cv,
                                                int M, int N, int K,
                                                const int* __restrict__ flag,
                                                int flag_mode) {
  __shared__ u16 Ash[2 * 256 * 64];
  __shared__ u16 Bsh[2 * 256 * 64];
  int tid = threadIdx.x, w = tid >> 6, lane = tid & 63;
  int quad = lane >> 4, l15 = lane & 15;
  int wr = w >> 2, wc = w & 3;
  int wm = wr * 128, wn = wc * 64;
  int m0 = blockIdx.y * 256, n0 = blockIdx.x * 256;
  int f32out = flag_mode ? (*flag > 1000) : 0;
  const int NT = K >> 6;

  int srow8 = lane >> 3;
  int gch = (lane & 7) ^ srow8;
  const u16* Ag = A + (size_t)(m0 + w * 8 + srow8) * K + gch * 8;
  const u16* Bg = Bm + (size_t)(n0 + w * 8 + srow8) * K + gch * 8;
  int ldsrow = w * 8;  // wave-uniform LDS row base; lane*16B added by HW

  floatx4 acc[8][4];
#pragma unroll
  for (int i = 0; i < 8; ++i)
#pragma unroll
    for (int j = 0; j < 4; ++j) acc[i][j] = floatx4{0.f, 0.f, 0.f, 0.f};

  int ch0 = ((quad ^ (l15 & 7)) << 3);        // kk=0 chunk byte-> u16 offset
  int ch1 = (((4 + quad) ^ (l15 & 7)) << 3);  // kk=1

  auto stage = [&](int qi) {
    int tau = qi >> 2;
    int tc = tau < NT ? tau : NT - 1;  // clamp keeps vmcnt counts exact
    int hh = qi & 3;                   // 0:B0 1:B1 2:A0 3:A1
    int half = (hh & 1) * 128;
    int sbuf = (tau & 1) * (256 * 64);
    size_t kof = (size_t)tc * 64;
    if (hh < 2) {
      gl_lds16(Bg + (size_t)half * K + kof,
               (void*)(Bsh + sbuf + (half + ldsrow) * 64));
      gl_lds16(Bg + (size_t)(half + 64) * K + kof,
               (void*)(Bsh + sbuf + (half + 64 + ldsrow) * 64));
    } else {
      gl_lds16(Ag + (size_t)half * K + kof,
               (void*)(Ash + sbuf + (half + ldsrow) * 64));
      gl_lds16(Ag + (size_t)(half + 64) * K + kof,
               (void*)(Ash + sbuf + (half + 64 + ldsrow) * 64));
    }
  };

  // Prologue: tile0 fully + 3 half-tiles of tile1 -> 3 half-tiles in flight.
  stage(0); stage(1); stage(2); stage(3);
  __asm__ volatile("s_waitcnt vmcnt(4)" ::: "memory");
  stage(4); stage(5); stage(6);
  __asm__ volatile("s_waitcnt vmcnt(6)" ::: "memory");
  __builtin_amdgcn_s_barrier();

  for (int t = 0; t < NT; ++t) {
    u16* As = Ash + (t & 1) * (256 * 64);
    u16* Bs = Bsh + (t & 1) * (256 * 64);
    if (t) {
      __asm__ volatile("s_waitcnt vmcnt(6)" ::: "memory");
      __builtin_amdgcn_s_barrier();
    }
    int qb = 7 + 4 * t;
    short8 bf[8], af0[8], af1[8];

    // ---- P0: read af0-kk0 + bf-kk0 (8 reads); MFMA mh0 x kk0 (16) ----
#pragma unroll
    for (int j = 0; j < 4; ++j) {
      int n = wn + 16 * j + l15;
      bf[2 * j] = *(const short8*)(Bs + n * 64 + ch0);
    }
#pragma unroll
    for (int i = 0; i < 4; ++i) {
      int m = wm + 16 * i + l15;
      af0[2 * i] = *(const short8*)(As + m * 64 + ch0);
    }
    stage(qb);
    __builtin_amdgcn_s_barrier();
    __asm__ volatile("s_waitcnt lgkmcnt(0)" ::: "memory");
    __builtin_amdgcn_sched_barrier(0);
    __builtin_amdgcn_s_setprio(1);
#pragma unroll
    for (int i = 0; i < 4; ++i)
#pragma unroll
      for (int j = 0; j < 4; ++j)
        acc[i][j] = MFMA16(af0[2 * i], bf[2 * j], acc[i][j]);
    __builtin_amdgcn_s_setprio(0);
    __builtin_amdgcn_s_barrier();

    // ---- P1: read af0-kk1 + bf-kk1 (8 reads); MFMA mh0 x kk1 (16) ----
#pragma unroll
    for (int j = 0; j < 4; ++j) {
      int n = wn + 16 * j + l15;
      bf[2 * j + 1] = *(const short8*)(Bs + n * 64 + ch1);
    }
#pragma unroll
    for (int i = 0; i < 4; ++i) {
      int m = wm + 16 * i + l15;
      af0[2 * i + 1] = *(const short8*)(As + m * 64 + ch1);
    }
    stage(qb + 1);
    __builtin_amdgcn_s_barrier();
    __asm__ volatile("s_waitcnt lgkmcnt(0)" ::: "memory");
    __builtin_amdgcn_sched_barrier(0);
    __builtin_amdgcn_s_setprio(1);
#pragma unroll
    for (int i = 0; i < 4; ++i)
#pragma unroll
      for (int j = 0; j < 4; ++j)
        acc[i][j] = MFMA16(af0[2 * i + 1], bf[2 * j + 1], acc[i][j]);
    __builtin_amdgcn_s_setprio(0);
    __builtin_amdgcn_s_barrier();

    // ---- P2: read af1-kk0 (4 reads); MFMA mh1 x kk0 (16) ----
#pragma unroll
    for (int i = 0; i < 4; ++i) {
      int m = wm + 64 + 16 * i + l15;
      af1[2 * i] = *(const short8*)(As + m * 64 + ch0);
    }
    stage(qb + 2);
    __builtin_amdgcn_s_barrier();
    __asm__ volatile("s_waitcnt lgkmcnt(0)" ::: "memory");
    __builtin_amdgcn_sched_barrier(0);
    __builtin_amdgcn_s_setprio(1);
#pragma unroll
    for (int i = 0; i < 4; ++i)
#pragma unroll
      for (int j = 0; j < 4; ++j)
        acc[4 + i][j] = MFMA16(af1[2 * i], bf[2 * j], acc[4 + i][j]);
    __builtin_amdgcn_s_setprio(0);
    __builtin_amdgcn_s_barrier();

    // ---- P3: read af1-kk1 (4 reads); MFMA mh1 x kk1 (16) ----
#pragma unroll
    for (int i = 0; i < 4; ++i) {
      int m = wm + 64 + 16 * i + l15;
      af1[2 * i + 1] = *(const short8*)(As + m * 64 + ch1);
    }
    stage(qb + 3);
    __builtin_amdgcn_s_barrier();
    __asm__ volatile("s_waitcnt lgkmcnt(0)" ::: "memory");
    __builtin_amdgcn_sched_barrier(0);
    __builtin_amdgcn_s_setprio(1);
#pragma unroll
    for (int i = 0; i < 4; ++i)
#pragma unroll
      for (int j = 0; j < 4; ++j)
        acc[4 + i][j] = MFMA16(af1[2 * i + 1], bf[2 * j + 1], acc[4 + i][j]);
    __builtin_amdgcn_s_setprio(0);
    __builtin_amdgcn_s_barrier();
  }

  // Epilogue (same C/D mapping as proven gemm_nt).
#pragma unroll
  for (int i = 0; i < 8; ++i)
#pragma unroll
    for (int r = 0; r < 4; ++r) {
      int row = m0 + wm + 16 * i + quad * 4 + r;
      if (f32out) {
        float* cp = (float*)Cv + (size_t)row * N + n0 + wn + l15;
#pragma unroll
        for (int j = 0; j < 4; ++j) cp[16 * j] = acc[i][j][r];
      } else {
        u16* cp = (u16*)Cv + (size_t)row * N + n0 + wn + l15;
#pragma unroll
        for (int j = 0; j < 4; ++j) cp[16 * j] = f2b(acc[i][j][r]);
      }
    }
}

// ---------------------------------------------------------------------------
// RoPE in-place; Q additionally scaled by 1/sqrt(dh) (folded from attention).
// ---------------------------------------------------------------------------
__global__ __launch_bounds__(256) void rope_kernel(u16* __restrict__ Q,
                                                   u16* __restrict__ KV) {
  const float scale = 0.08838834764831845f;  // 1/sqrt(128)
  int idx = blockIdx.x * 256 + threadIdx.x;
  int tok = idx >> 10;
  int rem = idx & 1023;
  int h = rem >> 6, i = rem & 63;
  int pos = tok & 2047;
  float f = __powf(10000.0f, -(float)(2 * i) * (1.0f / 128.0f));
  float ang = (float)pos * f;
  float s, c;
  sincosf(ang, &s, &c);

  size_t qb = (size_t)tok * 2048 + h * 128 + i;
  float q1 = b2f(Q[qb]), q2 = b2f(Q[qb + 64]);
  Q[qb] = f2b((q1 * c - q2 * s) * scale);
  Q[qb + 64] = f2b((q2 * c + q1 * s) * scale);

  size_t kb = (size_t)tok * 4096 + h * 128 + i;
  float k1 = b2f(KV[kb]), k2 = b2f(KV[kb + 64]);
  KV[kb] = f2b(k1 * c - k2 * s);
  KV[kb + 64] = f2b(k2 * c + k1 * s);
}

// ---------------------------------------------------------------------------
// Flash attention v9: LDS cut to EXACTLY 64 KiB (K single-buffered, V dbuf,
// P 16K) so TWO 512-thread blocks co-reside per CU (2x64=128 <= 160 KiB;
// R5's 80 KiB needed exactly 160 and failed to co-place). Grid 512 blocks
// (32 bh x 16 qt, heavy-first LPT). Per iter: QK^T(K) | bar#1 (closes all
// K reads) | stage K(t+1)+V(t+1,buf^1) | softmax+PV (hides stage latency) |
// bar#2 (drains stages). Stage-after-read invariant holds block-wide.
// ---------------------------------------------------------------------------
__global__ __launch_bounds__(512, 1) void flash_attn(const u16* __restrict__ Q,
                                                     const u16* __restrict__ KV,
                                                     const u16* __restrict__ Vt,
                                                     u16* __restrict__ O) {
  const int S = 2048, D = 2048, KVld = 4096;
  int bh = blockIdx.x;            // 0..31
  int qt = 15 - (int)blockIdx.y;  // heavy-first dispatch
  int b = bh >> 4, h = bh & 15;
  int tid = threadIdx.x, w = tid >> 6, lane = tid & 63;
  int quad = lane >> 4, l15 = lane & 15;

  const u16* Qb = Q + (size_t)(b * S) * D + h * 128;
  const u16* Kb = KV + (size_t)(b * S) * KVld + h * 128;
  const u16* Vtb = Vt + ((size_t)(b * 2048 + h * 128)) * S;

  __shared__ u16 Ksh[64 * 128];     // single buffer [krow][d], chunk ^= krow&7
  __shared__ u16 Vsh[2][128 * 64];  // dbuf [d][k], chunk ^= d&7
  __shared__ u16 Psh[8][16 * 64];   // per-wave P

  auto stage_k = [&](int kt) {
    int kb = kt * 64;
#pragma unroll
    for (int tt = 0; tt < 2; ++tt) {
      int r0 = w * 8 + tt * 4;
      int row = r0 + quad;
      int g = (l15 & 8) | ((l15 & 7) ^ (row & 7));
      gl_lds16(Kb + (size_t)(kb + row) * KVld + g * 8, (void*)(Ksh + r0 * 128));
    }
  };
  auto stage_v = [&](int kt, int buf) {
    int kb = kt * 64;
#pragma unroll
    for (int tt = 0; tt < 2; ++tt) {
      int d0 = w * 16 + tt * 8;
      int d = d0 + (lane >> 3);
      int g = (lane & 7) ^ (d & 7);
      gl_lds16(Vtb + (size_t)d * S + kb + g * 8, (void*)(Vsh[buf] + d0 * 64));
    }
  };

  int qw = qt * 128 + w * 16;  // this wave's 16 q-rows

  short8 qf[4];
  {
    const u16* qp = Qb + (size_t)(qw + l15) * D + quad * 8;
#pragma unroll
    for (int kk = 0; kk < 4; ++kk) qf[kk] = *(const short8*)(qp + kk * 32);
  }

  floatx4 o[8];
#pragma unroll
  for (int t = 0; t < 8; ++t) o[t] = floatx4{0.f, 0.f, 0.f, 0.f};
  float mrow[4], lrow[4];
#pragma unroll
  for (int r = 0; r < 4; ++r) { mrow[r] = -1e30f; lrow[r] = 0.f; }

  int nk = 2 * qt + 2;
  stage_k(0);
  stage_v(0, 0);
  __syncthreads();

  for (int kt = 0; kt < nk; ++kt) {
    int kb = kt * 64;
    int cur = kt & 1;
    bool act = (kb <= qw + 15);

    // --- QK^T: 4n x 4ksteps = 16 MFMA (reads Ksh) ---
    floatx4 sc[4];
    if (act) {
#pragma unroll
      for (int nf = 0; nf < 4; ++nf) sc[nf] = floatx4{0.f, 0.f, 0.f, 0.f};
#pragma unroll
      for (int kk = 0; kk < 4; ++kk) {
        int c = kk * 4 + quad;
        short8 kf[4];
#pragma unroll
        for (int nf = 0; nf < 4; ++nf) {
          int n = nf * 16 + l15;
          int pc = (c & 8) | ((c & 7) ^ (n & 7));
          kf[nf] = *(const short8*)(Ksh + n * 128 + pc * 8);
        }
#pragma unroll
        for (int nf = 0; nf < 4; ++nf) sc[nf] = MFMA16(qf[kk], kf[nf], sc[nf]);
      }
    }
    // #1: all waves' K reads complete (syncthreads drains each wave's lgkm)
    __syncthreads();
    // prefetch next tile: K into the (now unread) single buffer, V into buf^1
    if (kt + 1 < nk) {
      stage_k(kt + 1);
      stage_v(kt + 1, cur ^ 1);
    }

    if (act) {
      // --- online softmax (1/sqrt(dh) pre-folded into Q) ---
      bool masked = (kb + 63 > qw);
      floatx4 alv;
#pragma unroll
      for (int r = 0; r < 4; ++r) {
        int qg = qw + quad * 4 + r;
        float v0 = sc[0][r], v1 = sc[1][r];
        float v2 = sc[2][r], v3 = sc[3][r];
        if (masked) {
          v0 = (kb + l15 <= qg) ? v0 : -1e30f;
          v1 = (kb + 16 + l15 <= qg) ? v1 : -1e30f;
          v2 = (kb + 32 + l15 <= qg) ? v2 : -1e30f;
          v3 = (kb + 48 + l15 <= qg) ? v3 : -1e30f;
        }
        float mx = max16(fmaxf(fmaxf(v0, v1), fmaxf(v2, v3)));
        float mn = fmaxf(mrow[r], mx);
        float al = __expf(mrow[r] - mn);
        mrow[r] = mn;
        float p0 = __expf(v0 - mn), p1 = __expf(v1 - mn);
        float p2 = __expf(v2 - mn), p3 = __expf(v3 - mn);
        float rs = sum16((p0 + p1) + (p2 + p3));
        lrow[r] = lrow[r] * al + rs;
        alv[r] = al;
        int m_ = quad * 4 + r;
        int sw = (m_ & 3) ^ ((m_ >> 2) << 1);
        int cb = l15 >> 3, e = l15 & 7;
        u16* pr = Psh[w] + m_ * 64;
        pr[(((0 + cb) ^ sw) << 3) + e] = f2b_rn(p0);
        pr[(((2 + cb) ^ sw) << 3) + e] = f2b_rn(p1);
        pr[(((4 + cb) ^ sw) << 3) + e] = f2b_rn(p2);
        pr[(((6 + cb) ^ sw) << 3) + e] = f2b_rn(p3);
      }
      // defer-rescale: al==1.0 exactly when the running max didn't grow.
      if (__any((alv[0] != 1.f) || (alv[1] != 1.f) ||
                (alv[2] != 1.f) || (alv[3] != 1.f))) {
#pragma unroll
        for (int t = 0; t < 8; ++t) o[t] *= alv;
      }
      __asm__ volatile("s_waitcnt lgkmcnt(0)" ::: "memory");

      // --- PV: 8d x 2ksteps = 16 MFMA (reads Vsh[cur] + Psh[w]) ---
#pragma unroll
      for (int ks = 0; ks < 2; ++ks) {
        int c = ks * 4 + quad;
        int psw = (l15 & 3) ^ ((l15 >> 2) << 1);
        short8 pf = *(const short8*)(Psh[w] + l15 * 64 + ((c ^ psw) << 3));
#pragma unroll
        for (int t = 0; t < 8; ++t) {
          int d = t * 16 + l15;
          short8 vf = *(const short8*)(Vsh[cur] + d * 64 + ((c ^ (d & 7)) << 3));
          o[t] = MFMA16(pf, vf, o[t]);
        }
      }
    }
    // #2: drains this wave's prefetch gl_lds (vmcnt) + joins waves; next
    // tile's K and V are valid past this point.
    __syncthreads();
  }

  // epilogue
#pragma unroll
  for (int r = 0; r < 4; ++r) {
    float inv = 1.0f / lrow[r];
    int qg = qw + quad * 4 + r;
    u16* op = O + (size_t)(b * S + qg) * D + h * 128;
#pragma unroll
    for (int t = 0; t < 8; ++t) op[t * 16 + l15] = f2b(o[t][r] * inv);
  }
}

// ---------------------------------------------------------------------------
// Launch. ws (u16 after 64-elem flag pad):
//   xb 8.4M | Wbuf 8.4M (wq -> wkvT -> Vt -> wo) | Qb 8.4M | KVb 16.8M
//   AO aliases xb. Total ~84 MB. flag[0] = large-exponent count (memset 0).
// ---------------------------------------------------------------------------
extern "C" void kernel_launch(void* const* d_in, const int* in_sizes, int n_in,
                              void* d_out, int out_size, void* d_ws, size_t ws_size,
                              hipStream_t stream) {
  const void* x = d_in[0];
  const void* wq = d_in[1];
  const void* wkv = d_in[2];
  const void* wo = d_in[3];

  int* flag = (int*)d_ws;
  u16* xb = (u16*)d_ws + 64;
  u16* Wbuf = xb + (size_t)8388608;
  u16* Qb = Wbuf + (size_t)8388608;
  u16* KVb = Qb + (size_t)8388608;
  u16* AO = xb;  // x dead after KV projection

  hipMemsetAsync(flag, 0, sizeof(int), stream);
  detect_f32<<<32, 256, 0, stream>>>((const u16*)x, flag);
  convert_in8<<<4096, 256, 0, stream>>>(x, xb, 1048576, flag);
  convert_in8<<<2048, 256, 0, stream>>>(wq, Wbuf, 524288, flag);
  gemm_nt<<<dim3(16, 32), 256, 0, stream>>>(xb, Wbuf, Qb, 4096, 2048, 2048, flag, 0);
  transpose_conv<<<dim3(128, 64), 256, 0, stream>>>(wkv, Wbuf, 2048, 4096, flag);
  gemm8<<<dim3(16, 16), 512, 0, stream>>>(xb, Wbuf, KVb, 4096, 4096, 2048, flag, 0);
  transpose_v<<<dim3(64, 64, 2), 256, 0, stream>>>(KVb, Wbuf);  // Wbuf := Vt
  rope_kernel<<<16384, 256, 0, stream>>>(Qb, KVb);
  flash_attn<<<dim3(32, 16), 512, 0, stream>>>(Qb, KVb, Wbuf, AO);
  convert_in8<<<2048, 256, 0, stream>>>(wo, Wbuf, 524288, flag);
  gemm_nt<<<dim3(16, 32), 256, 0, stream>>>(AO, Wbuf, d_out, 4096, 2048, 2048, flag, 1);
}

// Round 10
// 414.001 us; speedup vs baseline: 1.1932x; 1.0114x over previous
//
#include <hip/hip_runtime.h>
#include <stdint.h>

typedef unsigned short u16;
typedef __attribute__((ext_vector_type(8))) short short8;
typedef __attribute__((ext_vector_type(4))) float floatx4;

#define MFMA16(a, b, c) __builtin_amdgcn_mfma_f32_16x16x32_bf16(a, b, c, 0, 0, 0)

static __device__ __forceinline__ void gl_lds16(const void* g, void* l) {
  __builtin_amdgcn_global_load_lds(
      (const __attribute__((address_space(1))) uint32_t*)g,
      (__attribute__((address_space(3))) uint32_t*)l, 16, 0, 0);
}

static __device__ __forceinline__ float b2f(u16 u) {
  union { float f; unsigned u; } v;
  v.u = ((unsigned)u) << 16;
  return v.f;
}
static __device__ __forceinline__ u16 f2b(float f) {
  union { float f; unsigned u; } v;
  v.f = f;
  unsigned r = v.u + 0x7fffu + ((v.u >> 16) & 1u);  // RNE
  return (u16)(r >> 16);
}
// Cheap round-half-up bf16 (2 VALU ops). P-store only (values in [0,1]).
static __device__ __forceinline__ u16 f2b_rn(float f) {
  union { float f; unsigned u; } v;
  v.f = f;
  return (u16)((v.u + 0x8000u) >> 16);
}

// DPP row-rotate reductions over 16-lane groups (VALU, no LDS traffic).
template <int CTRL>
static __device__ __forceinline__ float dppf(float x) {
  return __builtin_bit_cast(
      float, __builtin_amdgcn_update_dpp(0, __builtin_bit_cast(int, x), CTRL,
                                         0xF, 0xF, true));
}
static __device__ __forceinline__ float sum16(float x) {
  x += dppf<0x128>(x);
  x += dppf<0x124>(x);
  x += dppf<0x122>(x);
  x += dppf<0x121>(x);
  return x;
}
static __device__ __forceinline__ float max16(float x) {
  x = fmaxf(x, dppf<0x128>(x));
  x = fmaxf(x, dppf<0x124>(x));
  x = fmaxf(x, dppf<0x122>(x));
  x = fmaxf(x, dppf<0x121>(x));
  return x;
}

// ---------------------------------------------------------------------------
// Input-dtype detector, PARALLEL (proven round 8: the 1-block serial version
// was a pipeline-gating latency chain worth tens of us).
// ---------------------------------------------------------------------------
__global__ __launch_bounds__(256) void detect_f32(const u16* __restrict__ x,
                                                  int* __restrict__ flag) {
  __shared__ int cnt[256];
  int i = blockIdx.x * 256 + threadIdx.x;  // 8192 threads x 8 u16 = 64K u16
  short8 v = ((const short8*)x)[i];
  int c = 0;
#pragma unroll
  for (int j = 0; j < 8; ++j) {
    int e = (((unsigned short)v[j]) >> 7) & 0xFF;
    c += (e >= 140) ? 1 : 0;
  }
  cnt[threadIdx.x] = c;
  __syncthreads();
  for (int s = 128; s > 0; s >>= 1) {
    if (threadIdx.x < (unsigned)s) cnt[threadIdx.x] += cnt[threadIdx.x + s];
    __syncthreads();
  }
  if (threadIdx.x == 0) atomicAdd(flag, cnt[0]);
}

// Vectorized flag-aware convert: 8 elems/thread.
__global__ __launch_bounds__(256) void convert_in8(const void* __restrict__ src,
                                                   u16* __restrict__ dst, int n8,
                                                   const int* __restrict__ flag) {
  int i = blockIdx.x * 256 + threadIdx.x;
  if (i >= n8) return;
  short8 r;
  if (*flag > 1000) {
    const float4* s = (const float4*)src;
    float4 a = s[2 * i], b = s[2 * i + 1];
    r[0] = (short)f2b(a.x); r[1] = (short)f2b(a.y);
    r[2] = (short)f2b(a.z); r[3] = (short)f2b(a.w);
    r[4] = (short)f2b(b.x); r[5] = (short)f2b(b.y);
    r[6] = (short)f2b(b.z); r[7] = (short)f2b(b.w);
  } else {
    r = ((const short8*)src)[i];
  }
  ((short8*)dst)[i] = r;
}

__global__ __launch_bounds__(256) void transpose_conv(const void* __restrict__ in,
                                                      u16* __restrict__ out,
                                                      int R, int Ccols,
                                                      const int* __restrict__ flag) {
  __shared__ u16 tile[32][33];
  int f = (*flag > 1000) ? 1 : 0;
  int c0 = blockIdx.x * 32, r0 = blockIdx.y * 32;
  int lx = threadIdx.x & 31, ly = threadIdx.x >> 5;
#pragma unroll
  for (int i = 0; i < 32; i += 8) {
    size_t idx = (size_t)(r0 + ly + i) * Ccols + c0 + lx;
    tile[ly + i][lx] = f ? f2b(((const float*)in)[idx]) : ((const u16*)in)[idx];
  }
  __syncthreads();
#pragma unroll
  for (int i = 0; i < 32; i += 8)
    out[(size_t)(c0 + ly + i) * R + r0 + lx] = tile[lx][ly + i];
}

// V half of KV [4096][4096] -> Vt[b][d][s]  ([2][2048][2048])
__global__ __launch_bounds__(256) void transpose_v(const u16* __restrict__ KV,
                                                   u16* __restrict__ Vt) {
  __shared__ u16 tile[32][33];
  int b = blockIdx.z;
  int d0 = blockIdx.x * 32, s0 = blockIdx.y * 32;
  int lx = threadIdx.x & 31, ly = threadIdx.x >> 5;
  const u16* src = KV + ((size_t)(b * 2048 + s0)) * 4096 + 2048 + d0;
#pragma unroll
  for (int i = 0; i < 32; i += 8)
    tile[ly + i][lx] = src[(size_t)(ly + i) * 4096 + lx];
  __syncthreads();
  u16* dst = Vt + ((size_t)(b * 2048 + d0)) * 2048 + s0;
#pragma unroll
  for (int i = 0; i < 32; i += 8)
    dst[(size_t)(ly + i) * 2048 + lx] = tile[lx][ly + i];
}

// ---------------------------------------------------------------------------
// NT GEMM (m97 structure, proven) — Q and O projections (512-block grids).
// ---------------------------------------------------------------------------
__global__ __launch_bounds__(256) void gemm_nt(const u16* __restrict__ A,
                                               const u16* __restrict__ Bm,
                                               void* __restrict__ Cv,
                                               int M, int N, int K,
                                               const int* __restrict__ flag,
                                               int flag_mode) {
  __shared__ u16 Ash[128 * 64];
  __shared__ u16 Bsh[128 * 64];
  int tid = threadIdx.x, w = tid >> 6, lane = tid & 63;
  int quad = lane >> 4, l15 = lane & 15;
  int m0 = blockIdx.y * 128, n0 = blockIdx.x * 128;
  int wm = (w & 1) * 64, wn = (w >> 1) * 64;
  int f32out = flag_mode ? (*flag > 1000) : 0;

  floatx4 acc[4][4];
#pragma unroll
  for (int i = 0; i < 4; ++i)
#pragma unroll
    for (int j = 0; j < 4; ++j) acc[i][j] = floatx4{0.f, 0.f, 0.f, 0.f};

  int srow = lane >> 3;
  int gch = (lane & 7) ^ srow;
  const u16* Ag = A + (size_t)(m0 + w * 32 + srow) * K + gch * 8;
  const u16* Bg = Bm + (size_t)(n0 + w * 32 + srow) * K + gch * 8;

  for (int k0 = 0; k0 < K; k0 += 64) {
    __syncthreads();
#pragma unroll
    for (int t = 0; t < 4; ++t) {
      gl_lds16(Ag + (size_t)t * 8 * K + k0, (void*)(Ash + (w * 32 + t * 8) * 64));
      gl_lds16(Bg + (size_t)t * 8 * K + k0, (void*)(Bsh + (w * 32 + t * 8) * 64));
    }
    __syncthreads();
#pragma unroll
    for (int kk = 0; kk < 2; ++kk) {
      int c = kk * 4 + quad;
      short8 af[4], bf[4];
#pragma unroll
      for (int i = 0; i < 4; ++i) {
        int m = wm + 16 * i + l15;
        af[i] = *(const short8*)(Ash + m * 64 + ((c ^ (m & 7)) << 3));
        int n = wn + 16 * i + l15;
        bf[i] = *(const short8*)(Bsh + n * 64 + ((c ^ (n & 7)) << 3));
      }
#pragma unroll
      for (int i = 0; i < 4; ++i)
#pragma unroll
        for (int j = 0; j < 4; ++j) acc[i][j] = MFMA16(af[i], bf[j], acc[i][j]);
    }
  }

#pragma unroll
  for (int i = 0; i < 4; ++i)
#pragma unroll
    for (int r = 0; r < 4; ++r) {
      int row = m0 + wm + 16 * i + quad * 4 + r;
      if (f32out) {
        float* cp = (float*)Cv + (size_t)row * N + n0 + wn + l15;
#pragma unroll
        for (int j = 0; j < 4; ++j) cp[16 * j] = acc[i][j][r];
      } else {
        u16* cp = (u16*)Cv + (size_t)row * N + n0 + wn + l15;
#pragma unroll
        for (int j = 0; j < 4; ++j) cp[16 * j] = f2b(acc[i][j][r]);
      }
    }
}

// ---------------------------------------------------------------------------
// 8-phase 256x256 NT GEMM (m201 template) — KV projection (grid 256, proven).
// ---------------------------------------------------------------------------
__global__ __launch_bounds__(512, 2) void gemm8(const u16* __restrict__ A,
                                                const u16* __restrict__ Bm,
                                                void* __restrict__ Cv,
                                                int M, int N, int K,
                                                const int* __restrict__ flag,
                                                int flag_mode) {
  __shared__ u16 Ash[2 * 256 * 64];
  __shared__ u16 Bsh[2 * 256 * 64];
  int tid = threadIdx.x, w = tid >> 6, lane = tid & 63;
  int quad = lane >> 4, l15 = lane & 15;
  int wr = w >> 2, wc = w & 3;
  int wm = wr * 128, wn = wc * 64;
  int m0 = blockIdx.y * 256, n0 = blockIdx.x * 256;
  int f32out = flag_mode ? (*flag > 1000) : 0;
  const int NT = K >> 6;

  int srow8 = lane >> 3;
  int gch = (lane & 7) ^ srow8;
  const u16* Ag = A + (size_t)(m0 + w * 8 + srow8) * K + gch * 8;
  const u16* Bg = Bm + (size_t)(n0 + w * 8 + srow8) * K + gch * 8;
  int ldsrow = w * 8;  // wave-uniform LDS row base; lane*16B added by HW

  floatx4 acc[8][4];
#pragma unroll
  for (int i = 0; i < 8; ++i)
#pragma unroll
    for (int j = 0; j < 4; ++j) acc[i][j] = floatx4{0.f, 0.f, 0.f, 0.f};

  int ch0 = ((quad ^ (l15 & 7)) << 3);        // kk=0 chunk byte-> u16 offset
  int ch1 = (((4 + quad) ^ (l15 & 7)) << 3);  // kk=1

  auto stage = [&](int qi) {
    int tau = qi >> 2;
    int tc = tau < NT ? tau : NT - 1;  // clamp keeps vmcnt counts exact
    int hh = qi & 3;                   // 0:B0 1:B1 2:A0 3:A1
    int half = (hh & 1) * 128;
    int sbuf = (tau & 1) * (256 * 64);
    size_t kof = (size_t)tc * 64;
    if (hh < 2) {
      gl_lds16(Bg + (size_t)half * K + kof,
               (void*)(Bsh + sbuf + (half + ldsrow) * 64));
      gl_lds16(Bg + (size_t)(half + 64) * K + kof,
               (void*)(Bsh + sbuf + (half + 64 + ldsrow) * 64));
    } else {
      gl_lds16(Ag + (size_t)half * K + kof,
               (void*)(Ash + sbuf + (half + ldsrow) * 64));
      gl_lds16(Ag + (size_t)(half + 64) * K + kof,
               (void*)(Ash + sbuf + (half + 64 + ldsrow) * 64));
    }
  };

  // Prologue: tile0 fully + 3 half-tiles of tile1 -> 3 half-tiles in flight.
  stage(0); stage(1); stage(2); stage(3);
  __asm__ volatile("s_waitcnt vmcnt(4)" ::: "memory");
  stage(4); stage(5); stage(6);
  __asm__ volatile("s_waitcnt vmcnt(6)" ::: "memory");
  __builtin_amdgcn_s_barrier();

  for (int t = 0; t < NT; ++t) {
    u16* As = Ash + (t & 1) * (256 * 64);
    u16* Bs = Bsh + (t & 1) * (256 * 64);
    if (t) {
      __asm__ volatile("s_waitcnt vmcnt(6)" ::: "memory");
      __builtin_amdgcn_s_barrier();
    }
    int qb = 7 + 4 * t;
    short8 bf[8], af0[8], af1[8];

    // ---- P0: read af0-kk0 + bf-kk0 (8 reads); MFMA mh0 x kk0 (16) ----
#pragma unroll
    for (int j = 0; j < 4; ++j) {
      int n = wn + 16 * j + l15;
      bf[2 * j] = *(const short8*)(Bs + n * 64 + ch0);
    }
#pragma unroll
    for (int i = 0; i < 4; ++i) {
      int m = wm + 16 * i + l15;
      af0[2 * i] = *(const short8*)(As + m * 64 + ch0);
    }
    stage(qb);
    __builtin_amdgcn_s_barrier();
    __asm__ volatile("s_waitcnt lgkmcnt(0)" ::: "memory");
    __builtin_amdgcn_sched_barrier(0);
    __builtin_amdgcn_s_setprio(1);
#pragma unroll
    for (int i = 0; i < 4; ++i)
#pragma unroll
      for (int j = 0; j < 4; ++j)
        acc[i][j] = MFMA16(af0[2 * i], bf[2 * j], acc[i][j]);
    __builtin_amdgcn_s_setprio(0);
    __builtin_amdgcn_s_barrier();

    // ---- P1: read af0-kk1 + bf-kk1 (8 reads); MFMA mh0 x kk1 (16) ----
#pragma unroll
    for (int j = 0; j < 4; ++j) {
      int n = wn + 16 * j + l15;
      bf[2 * j + 1] = *(const short8*)(Bs + n * 64 + ch1);
    }
#pragma unroll
    for (int i = 0; i < 4; ++i) {
      int m = wm + 16 * i + l15;
      af0[2 * i + 1] = *(const short8*)(As + m * 64 + ch1);
    }
    stage(qb + 1);
    __builtin_amdgcn_s_barrier();
    __asm__ volatile("s_waitcnt lgkmcnt(0)" ::: "memory");
    __builtin_amdgcn_sched_barrier(0);
    __builtin_amdgcn_s_setprio(1);
#pragma unroll
    for (int i = 0; i < 4; ++i)
#pragma unroll
      for (int j = 0; j < 4; ++j)
        acc[i][j] = MFMA16(af0[2 * i + 1], bf[2 * j + 1], acc[i][j]);
    __builtin_amdgcn_s_setprio(0);
    __builtin_amdgcn_s_barrier();

    // ---- P2: read af1-kk0 (4 reads); MFMA mh1 x kk0 (16) ----
#pragma unroll
    for (int i = 0; i < 4; ++i) {
      int m = wm + 64 + 16 * i + l15;
      af1[2 * i] = *(const short8*)(As + m * 64 + ch0);
    }
    stage(qb + 2);
    __builtin_amdgcn_s_barrier();
    __asm__ volatile("s_waitcnt lgkmcnt(0)" ::: "memory");
    __builtin_amdgcn_sched_barrier(0);
    __builtin_amdgcn_s_setprio(1);
#pragma unroll
    for (int i = 0; i < 4; ++i)
#pragma unroll
      for (int j = 0; j < 4; ++j)
        acc[4 + i][j] = MFMA16(af1[2 * i], bf[2 * j], acc[4 + i][j]);
    __builtin_amdgcn_s_setprio(0);
    __builtin_amdgcn_s_barrier();

    // ---- P3: read af1-kk1 (4 reads); MFMA mh1 x kk1 (16) ----
#pragma unroll
    for (int i = 0; i < 4; ++i) {
      int m = wm + 64 + 16 * i + l15;
      af1[2 * i + 1] = *(const short8*)(As + m * 64 + ch1);
    }
    stage(qb + 3);
    __builtin_amdgcn_s_barrier();
    __asm__ volatile("s_waitcnt lgkmcnt(0)" ::: "memory");
    __builtin_amdgcn_sched_barrier(0);
    __builtin_amdgcn_s_setprio(1);
#pragma unroll
    for (int i = 0; i < 4; ++i)
#pragma unroll
      for (int j = 0; j < 4; ++j)
        acc[4 + i][j] = MFMA16(af1[2 * i + 1], bf[2 * j + 1], acc[4 + i][j]);
    __builtin_amdgcn_s_setprio(0);
    __builtin_amdgcn_s_barrier();
  }

  // Epilogue (same C/D mapping as proven gemm_nt).
#pragma unroll
  for (int i = 0; i < 8; ++i)
#pragma unroll
    for (int r = 0; r < 4; ++r) {
      int row = m0 + wm + 16 * i + quad * 4 + r;
      if (f32out) {
        float* cp = (float*)Cv + (size_t)row * N + n0 + wn + l15;
#pragma unroll
        for (int j = 0; j < 4; ++j) cp[16 * j] = acc[i][j][r];
      } else {
        u16* cp = (u16*)Cv + (size_t)row * N + n0 + wn + l15;
#pragma unroll
        for (int j = 0; j < 4; ++j) cp[16 * j] = f2b(acc[i][j][r]);
      }
    }
}

// ---------------------------------------------------------------------------
// RoPE in-place; Q additionally scaled by 1/sqrt(dh) (folded from attention).
// ---------------------------------------------------------------------------
__global__ __launch_bounds__(256) void rope_kernel(u16* __restrict__ Q,
                                                   u16* __restrict__ KV) {
  const float scale = 0.08838834764831845f;  // 1/sqrt(128)
  int idx = blockIdx.x * 256 + threadIdx.x;
  int tok = idx >> 10;
  int rem = idx & 1023;
  int h = rem >> 6, i = rem & 63;
  int pos = tok & 2047;
  float f = __powf(10000.0f, -(float)(2 * i) * (1.0f / 128.0f));
  float ang = (float)pos * f;
  float s, c;
  sincosf(ang, &s, &c);

  size_t qb = (size_t)tok * 2048 + h * 128 + i;
  float q1 = b2f(Q[qb]), q2 = b2f(Q[qb + 64]);
  Q[qb] = f2b((q1 * c - q2 * s) * scale);
  Q[qb + 64] = f2b((q2 * c + q1 * s) * scale);

  size_t kb = (size_t)tok * 4096 + h * 128 + i;
  float k1 = b2f(KV[kb]), k2 = b2f(KV[kb + 64]);
  KV[kb] = f2b(k1 * c - k2 * s);
  KV[kb + 64] = f2b(k2 * c + k1 * s);
}

// ---------------------------------------------------------------------------
// Flash attention v10: v9 structure with KVBLK 64 -> 128. Rationale (round-8
// counters): softmax VALU is the bound and ~half of it is per-tile FIXED cost
// (DPP trees, o-rescale, barriers, staging cadence). Doubling the k-tile
// halves fixed cost per unit work: trees 64->32, rescale 64->32, barriers
// 4->2 per 128 k. LDS 128 KiB (K 32K single-buf, V 2x32K dbuf, P 32K);
// occupancy stays 1 block/CU (proven insensitive). Chunk swizzles extend
// 8->16 chunks, same low-3-bit XOR. Stage-after-read invariant: K staged
// after bar#1 (closes all K reads), V into buf^1.
// ---------------------------------------------------------------------------
__global__ __launch_bounds__(512, 1) void flash_attn(const u16* __restrict__ Q,
                                                     const u16* __restrict__ KV,
                                                     const u16* __restrict__ Vt,
                                                     u16* __restrict__ O) {
  const int S = 2048, D = 2048, KVld = 4096;
  int bh = blockIdx.x;            // 0..31
  int qt = 15 - (int)blockIdx.y;  // heavy-first dispatch
  int b = bh >> 4, h = bh & 15;
  int tid = threadIdx.x, w = tid >> 6, lane = tid & 63;
  int quad = lane >> 4, l15 = lane & 15;

  const u16* Qb = Q + (size_t)(b * S) * D + h * 128;
  const u16* Kb = KV + (size_t)(b * S) * KVld + h * 128;
  const u16* Vtb = Vt + ((size_t)(b * 2048 + h * 128)) * S;

  __shared__ u16 Ksh[128 * 128];     // single buf [krow][d], 16 chunks/row
  __shared__ u16 Vsh[2][128 * 128];  // dbuf [d][k], 16 chunks/row
  __shared__ u16 Psh[8][16 * 128];   // per-wave P [16 q][128 k]

  // K tile [128 rows][128 d]: wave w rows w*16..w*16+16, 4 instrs.
  auto stage_k = [&](int kt) {
    int kb = kt * 128;
#pragma unroll
    for (int tt = 0; tt < 4; ++tt) {
      int r0 = w * 16 + tt * 4;
      int row = r0 + quad;
      int g = (l15 & 8) | ((l15 & 7) ^ (row & 7));
      gl_lds16(Kb + (size_t)(kb + row) * KVld + g * 8, (void*)(Ksh + r0 * 128));
    }
  };
  // V^T tile [128 d][128 k]: wave w d-rows w*16..w*16+16, 4 instrs.
  auto stage_v = [&](int kt, int buf) {
    int kb = kt * 128;
#pragma unroll
    for (int tt = 0; tt < 4; ++tt) {
      int d0 = w * 16 + tt * 4;
      int d = d0 + quad;
      int g = (l15 & 8) | ((l15 & 7) ^ (d & 7));
      gl_lds16(Vtb + (size_t)d * S + kb + g * 8, (void*)(Vsh[buf] + d0 * 128));
    }
  };

  int qw = qt * 128 + w * 16;  // this wave's 16 q-rows

  short8 qf[4];
  {
    const u16* qp = Qb + (size_t)(qw + l15) * D + quad * 8;
#pragma unroll
    for (int kk = 0; kk < 4; ++kk) qf[kk] = *(const short8*)(qp + kk * 32);
  }

  floatx4 o[8];
#pragma unroll
  for (int t = 0; t < 8; ++t) o[t] = floatx4{0.f, 0.f, 0.f, 0.f};
  float mrow[4], lrow[4];
#pragma unroll
  for (int r = 0; r < 4; ++r) { mrow[r] = -1e30f; lrow[r] = 0.f; }

  int nk = qt + 1;  // 128-wide k-tiles
  stage_k(0);
  stage_v(0, 0);
  __syncthreads();

  for (int kt = 0; kt < nk; ++kt) {
    int kb = kt * 128;
    int cur = kt & 1;

    // --- QK^T: 8 nf x 4 kk = 32 MFMA (reads Ksh) ---
    floatx4 sc[8];
#pragma unroll
    for (int nf = 0; nf < 8; ++nf) sc[nf] = floatx4{0.f, 0.f, 0.f, 0.f};
#pragma unroll
    for (int kk = 0; kk < 4; ++kk) {
      int c = kk * 4 + quad;
#pragma unroll
      for (int nf = 0; nf < 8; ++nf) {
        int n = nf * 16 + l15;
        int pc = (c & 8) | ((c & 7) ^ (n & 7));
        short8 kf = *(const short8*)(Ksh + n * 128 + pc * 8);
        sc[nf] = MFMA16(qf[kk], kf, sc[nf]);
      }
    }
    // #1: all waves' K reads complete
    __syncthreads();
    // prefetch next tile: K into the (now unread) single buffer, V into buf^1
    if (kt + 1 < nk) {
      stage_k(kt + 1);
      stage_v(kt + 1, cur ^ 1);
    }

    // --- online softmax (1/sqrt(dh) pre-folded into Q) ---
    bool masked = (kb + 127 > qw);
    floatx4 alv;
#pragma unroll
    for (int r = 0; r < 4; ++r) {
      int qg = qw + quad * 4 + r;
      float p[8];
#pragma unroll
      for (int g = 0; g < 8; ++g) {
        float vg = sc[g][r];
        if (masked) vg = (kb + 16 * g + l15 <= qg) ? vg : -1e30f;
        p[g] = vg;
      }
      float mx = fmaxf(fmaxf(fmaxf(p[0], p[1]), fmaxf(p[2], p[3])),
                       fmaxf(fmaxf(p[4], p[5]), fmaxf(p[6], p[7])));
      mx = max16(mx);
      float mn = fmaxf(mrow[r], mx);
      float al = __expf(mrow[r] - mn);
      mrow[r] = mn;
      float rs = 0.f;
#pragma unroll
      for (int g = 0; g < 8; ++g) {
        p[g] = __expf(p[g] - mn);
        rs += p[g];
      }
      rs = sum16(rs);
      lrow[r] = lrow[r] * al + rs;
      alv[r] = al;
      int m_ = quad * 4 + r;
      int sw = (m_ & 3) ^ ((m_ >> 2) << 1);
      int cb = l15 >> 3, e = l15 & 7;
      u16* pr = Psh[w] + m_ * 128;
#pragma unroll
      for (int g = 0; g < 8; ++g)
        pr[(((2 * g + cb) ^ sw) << 3) + e] = f2b_rn(p[g]);
    }
    // defer-rescale: al==1.0 exactly when the running max didn't grow.
    if (__any((alv[0] != 1.f) || (alv[1] != 1.f) ||
              (alv[2] != 1.f) || (alv[3] != 1.f))) {
#pragma unroll
      for (int t = 0; t < 8; ++t) o[t] *= alv;
    }
    __asm__ volatile("s_waitcnt lgkmcnt(0)" ::: "memory");

    // --- PV: 8 d x 4 ksteps = 32 MFMA (reads Vsh[cur] + Psh[w]) ---
    int psw = (l15 & 3) ^ ((l15 >> 2) << 1);
#pragma unroll
    for (int ks = 0; ks < 4; ++ks) {
      int c = ks * 4 + quad;
      short8 pf = *(const short8*)(Psh[w] + l15 * 128 + ((c ^ psw) << 3));
#pragma unroll
      for (int t = 0; t < 8; ++t) {
        int d = t * 16 + l15;
        int pc = (c & 8) | ((c & 7) ^ (d & 7));
        short8 vf = *(const short8*)(Vsh[cur] + d * 128 + pc * 8);
        o[t] = MFMA16(pf, vf, o[t]);
      }
    }
    // #2: drains this wave's prefetch gl_lds + joins waves.
    __syncthreads();
  }

  // epilogue
#pragma unroll
  for (int r = 0; r < 4; ++r) {
    float inv = 1.0f / lrow[r];
    int qg = qw + quad * 4 + r;
    u16* op = O + (size_t)(b * S + qg) * D + h * 128;
#pragma unroll
    for (int t = 0; t < 8; ++t) op[t * 16 + l15] = f2b(o[t][r] * inv);
  }
}

// ---------------------------------------------------------------------------
// Launch. ws (u16 after 64-elem flag pad):
//   xb 8.4M | Wbuf 8.4M (wq -> wkvT -> Vt -> wo) | Qb 8.4M | KVb 16.8M
//   AO aliases xb. Total ~84 MB. flag[0] = large-exponent count (memset 0).
// ---------------------------------------------------------------------------
extern "C" void kernel_launch(void* const* d_in, const int* in_sizes, int n_in,
                              void* d_out, int out_size, void* d_ws, size_t ws_size,
                              hipStream_t stream) {
  const void* x = d_in[0];
  const void* wq = d_in[1];
  const void* wkv = d_in[2];
  const void* wo = d_in[3];

  int* flag = (int*)d_ws;
  u16* xb = (u16*)d_ws + 64;
  u16* Wbuf = xb + (size_t)8388608;
  u16* Qb = Wbuf + (size_t)8388608;
  u16* KVb = Qb + (size_t)8388608;
  u16* AO = xb;  // x dead after KV projection

  hipMemsetAsync(flag, 0, sizeof(int), stream);
  detect_f32<<<32, 256, 0, stream>>>((const u16*)x, flag);
  convert_in8<<<4096, 256, 0, stream>>>(x, xb, 1048576, flag);
  convert_in8<<<2048, 256, 0, stream>>>(wq, Wbuf, 524288, flag);
  gemm_nt<<<dim3(16, 32), 256, 0, stream>>>(xb, Wbuf, Qb, 4096, 2048, 2048, flag, 0);
  transpose_conv<<<dim3(128, 64), 256, 0, stream>>>(wkv, Wbuf, 2048, 4096, flag);
  gemm8<<<dim3(16, 16), 512, 0, stream>>>(xb, Wbuf, KVb, 4096, 4096, 2048, flag, 0);
  transpose_v<<<dim3(64, 64, 2), 256, 0, stream>>>(KVb, Wbuf);  // Wbuf := Vt
  rope_kernel<<<16384, 256, 0, stream>>>(Qb, KVb);
  flash_attn<<<dim3(32, 16), 512, 0, stream>>>(Qb, KVb, Wbuf, AO);
  convert_in8<<<2048, 256, 0, stream>>>(wo, Wbuf, 524288, flag);
  gemm_nt<<<dim3(16, 32), 256, 0, stream>>>(AO, Wbuf, d_out, 4096, 2048, 2048, flag, 1);
}

// Round 11
// 405.050 us; speedup vs baseline: 1.2196x; 1.0221x over previous
//
#include <hip/hip_runtime.h>
#include <stdint.h>

typedef unsigned short u16;
typedef __attribute__((ext_vector_type(8))) short short8;
typedef __attribute__((ext_vector_type(4))) float floatx4;

#define MFMA16(a, b, c) __builtin_amdgcn_mfma_f32_16x16x32_bf16(a, b, c, 0, 0, 0)

static __device__ __forceinline__ void gl_lds16(const void* g, void* l) {
  __builtin_amdgcn_global_load_lds(
      (const __attribute__((address_space(1))) uint32_t*)g,
      (__attribute__((address_space(3))) uint32_t*)l, 16, 0, 0);
}

static __device__ __forceinline__ float b2f(u16 u) {
  union { float f; unsigned u; } v;
  v.u = ((unsigned)u) << 16;
  return v.f;
}
static __device__ __forceinline__ u16 f2b(float f) {
  union { float f; unsigned u; } v;
  v.f = f;
  unsigned r = v.u + 0x7fffu + ((v.u >> 16) & 1u);  // RNE
  return (u16)(r >> 16);
}
// Cheap round-half-up bf16 (2 VALU ops). P-store only (values in [0,1]).
static __device__ __forceinline__ u16 f2b_rn(float f) {
  union { float f; unsigned u; } v;
  v.f = f;
  return (u16)((v.u + 0x8000u) >> 16);
}

// flag[0..31]: per-block large-exponent counts (plain stores from detect;
// idempotent across graph replays — no memset node needed).
static __device__ __forceinline__ int is_f32(const int* __restrict__ flag) {
  int s = 0;
#pragma unroll
  for (int i = 0; i < 32; ++i) s += flag[i];
  return s > 1000;
}

// DPP row-rotate reductions over 16-lane groups (VALU, no LDS traffic).
template <int CTRL>
static __device__ __forceinline__ float dppf(float x) {
  return __builtin_bit_cast(
      float, __builtin_amdgcn_update_dpp(0, __builtin_bit_cast(int, x), CTRL,
                                         0xF, 0xF, true));
}
static __device__ __forceinline__ float sum16(float x) {
  x += dppf<0x128>(x);
  x += dppf<0x124>(x);
  x += dppf<0x122>(x);
  x += dppf<0x121>(x);
  return x;
}
static __device__ __forceinline__ float max16(float x) {
  x = fmaxf(x, dppf<0x128>(x));
  x = fmaxf(x, dppf<0x124>(x));
  x = fmaxf(x, dppf<0x122>(x));
  x = fmaxf(x, dppf<0x121>(x));
  return x;
}

// ---------------------------------------------------------------------------
// Input-dtype detector (parallel, proven round 8). Round 11: per-block plain
// stores to flag[bid] replace memset+atomicAdd (one fewer graph node;
// idempotent across replays).
// ---------------------------------------------------------------------------
__global__ __launch_bounds__(256) void detect_f32(const u16* __restrict__ x,
                                                  int* __restrict__ flag) {
  __shared__ int cnt[256];
  int i = blockIdx.x * 256 + threadIdx.x;  // 8192 threads x 8 u16 = 64K u16
  short8 v = ((const short8*)x)[i];
  int c = 0;
#pragma unroll
  for (int j = 0; j < 8; ++j) {
    int e = (((unsigned short)v[j]) >> 7) & 0xFF;
    c += (e >= 140) ? 1 : 0;
  }
  cnt[threadIdx.x] = c;
  __syncthreads();
  for (int s = 128; s > 0; s >>= 1) {
    if (threadIdx.x < (unsigned)s) cnt[threadIdx.x] += cnt[threadIdx.x + s];
    __syncthreads();
  }
  if (threadIdx.x == 0) flag[blockIdx.x] = cnt[0];
}

static __device__ __forceinline__ void conv8_body(const void* __restrict__ src,
                                                  u16* __restrict__ dst, int i,
                                                  int f32) {
  short8 r;
  if (f32) {
    const float4* s = (const float4*)src;
    float4 a = s[2 * i], b = s[2 * i + 1];
    r[0] = (short)f2b(a.x); r[1] = (short)f2b(a.y);
    r[2] = (short)f2b(a.z); r[3] = (short)f2b(a.w);
    r[4] = (short)f2b(b.x); r[5] = (short)f2b(b.y);
    r[6] = (short)f2b(b.z); r[7] = (short)f2b(b.w);
  } else {
    r = ((const short8*)src)[i];
  }
  ((short8*)dst)[i] = r;
}

// Standalone convert (wo, post-flash).
__global__ __launch_bounds__(256) void convert_in8(const void* __restrict__ src,
                                                   u16* __restrict__ dst, int n8,
                                                   const int* __restrict__ flag) {
  int i = blockIdx.x * 256 + threadIdx.x;
  if (i >= n8) return;
  conv8_body(src, dst, i, is_f32(flag));
}

// ---------------------------------------------------------------------------
// prep_fused (round 11): convert x (bid<4096) + convert wq (bid<6144, into
// KVb upper half — dead region until KV GEMM, read by Q GEMM first) +
// transpose wkv -> Wbuf (bid<14336). Whole blocks per branch.
// ---------------------------------------------------------------------------
__global__ __launch_bounds__(256) void prep_fused(const void* __restrict__ x,
                                                  const void* __restrict__ wq,
                                                  const void* __restrict__ wkv,
                                                  u16* __restrict__ xb,
                                                  u16* __restrict__ wqb,
                                                  u16* __restrict__ wkvT,
                                                  const int* __restrict__ flag) {
  __shared__ u16 tile[32][33];
  int bid = blockIdx.x;
  int f = is_f32(flag);
  if (bid < 4096) {
    conv8_body(x, xb, bid * 256 + threadIdx.x, f);
  } else if (bid < 6144) {
    conv8_body(wq, wqb, (bid - 4096) * 256 + threadIdx.x, f);
  } else {
    int tb = bid - 6144;  // 0..8191: wkv [2048][4096] -> wkvT [4096][2048]
    int c0 = (tb & 127) * 32, r0 = (tb >> 7) * 32;
    int lx = threadIdx.x & 31, ly = threadIdx.x >> 5;
#pragma unroll
    for (int i = 0; i < 32; i += 8) {
      size_t idx = (size_t)(r0 + ly + i) * 4096 + c0 + lx;
      tile[ly + i][lx] = f ? f2b(((const float*)wkv)[idx]) : ((const u16*)wkv)[idx];
    }
    __syncthreads();
#pragma unroll
    for (int i = 0; i < 32; i += 8)
      wkvT[(size_t)(c0 + ly + i) * 2048 + r0 + lx] = tile[lx][ly + i];
  }
}

// ---------------------------------------------------------------------------
// mid_fused (round 11): transpose_v (bid<8192; KVb V-cols -> Vt) + rope
// (bid>=8192; Qb + KVb K-cols in place). Regions disjoint — no sync needed.
// ---------------------------------------------------------------------------
__global__ __launch_bounds__(256) void mid_fused(u16* __restrict__ KV,
                                                 u16* __restrict__ Vt,
                                                 u16* __restrict__ Q) {
  __shared__ u16 tile[32][33];
  int bid = blockIdx.x;
  if (bid < 8192) {
    int b = bid >> 12;
    int d0 = (bid & 63) * 32, s0 = ((bid >> 6) & 63) * 32;
    int lx = threadIdx.x & 31, ly = threadIdx.x >> 5;
    const u16* src = KV + ((size_t)(b * 2048 + s0)) * 4096 + 2048 + d0;
#pragma unroll
    for (int i = 0; i < 32; i += 8)
      tile[ly + i][lx] = src[(size_t)(ly + i) * 4096 + lx];
    __syncthreads();
    u16* dst = Vt + ((size_t)(b * 2048 + d0)) * 2048 + s0;
#pragma unroll
    for (int i = 0; i < 32; i += 8)
      dst[(size_t)(ly + i) * 2048 + lx] = tile[lx][ly + i];
  } else {
    const float scale = 0.08838834764831845f;  // 1/sqrt(128)
    int idx = (bid - 8192) * 256 + threadIdx.x;
    int tok = idx >> 10;
    int rem = idx & 1023;
    int h = rem >> 6, i = rem & 63;
    int pos = tok & 2047;
    float f = __powf(10000.0f, -(float)(2 * i) * (1.0f / 128.0f));
    float ang = (float)pos * f;
    float s, c;
    sincosf(ang, &s, &c);

    size_t qb = (size_t)tok * 2048 + h * 128 + i;
    float q1 = b2f(Q[qb]), q2 = b2f(Q[qb + 64]);
    Q[qb] = f2b((q1 * c - q2 * s) * scale);
    Q[qb + 64] = f2b((q2 * c + q1 * s) * scale);

    size_t kb = (size_t)tok * 4096 + h * 128 + i;
    float k1 = b2f(KV[kb]), k2 = b2f(KV[kb + 64]);
    KV[kb] = f2b(k1 * c - k2 * s);
    KV[kb + 64] = f2b(k2 * c + k1 * s);
  }
}

// ---------------------------------------------------------------------------
// NT GEMM (m97 structure, proven) — Q and O projections (512-block grids).
// ---------------------------------------------------------------------------
__global__ __launch_bounds__(256) void gemm_nt(const u16* __restrict__ A,
                                               const u16* __restrict__ Bm,
                                               void* __restrict__ Cv,
                                               int M, int N, int K,
                                               const int* __restrict__ flag,
                                               int flag_mode) {
  __shared__ u16 Ash[128 * 64];
  __shared__ u16 Bsh[128 * 64];
  int tid = threadIdx.x, w = tid >> 6, lane = tid & 63;
  int quad = lane >> 4, l15 = lane & 15;
  int m0 = blockIdx.y * 128, n0 = blockIdx.x * 128;
  int wm = (w & 1) * 64, wn = (w >> 1) * 64;
  int f32out = flag_mode ? is_f32(flag) : 0;

  floatx4 acc[4][4];
#pragma unroll
  for (int i = 0; i < 4; ++i)
#pragma unroll
    for (int j = 0; j < 4; ++j) acc[i][j] = floatx4{0.f, 0.f, 0.f, 0.f};

  int srow = lane >> 3;
  int gch = (lane & 7) ^ srow;
  const u16* Ag = A + (size_t)(m0 + w * 32 + srow) * K + gch * 8;
  const u16* Bg = Bm + (size_t)(n0 + w * 32 + srow) * K + gch * 8;

  for (int k0 = 0; k0 < K; k0 += 64) {
    __syncthreads();
#pragma unroll
    for (int t = 0; t < 4; ++t) {
      gl_lds16(Ag + (size_t)t * 8 * K + k0, (void*)(Ash + (w * 32 + t * 8) * 64));
      gl_lds16(Bg + (size_t)t * 8 * K + k0, (void*)(Bsh + (w * 32 + t * 8) * 64));
    }
    __syncthreads();
#pragma unroll
    for (int kk = 0; kk < 2; ++kk) {
      int c = kk * 4 + quad;
      short8 af[4], bf[4];
#pragma unroll
      for (int i = 0; i < 4; ++i) {
        int m = wm + 16 * i + l15;
        af[i] = *(const short8*)(Ash + m * 64 + ((c ^ (m & 7)) << 3));
        int n = wn + 16 * i + l15;
        bf[i] = *(const short8*)(Bsh + n * 64 + ((c ^ (n & 7)) << 3));
      }
#pragma unroll
      for (int i = 0; i < 4; ++i)
#pragma unroll
        for (int j = 0; j < 4; ++j) acc[i][j] = MFMA16(af[i], bf[j], acc[i][j]);
    }
  }

#pragma unroll
  for (int i = 0; i < 4; ++i)
#pragma unroll
    for (int r = 0; r < 4; ++r) {
      int row = m0 + wm + 16 * i + quad * 4 + r;
      if (f32out) {
        float* cp = (float*)Cv + (size_t)row * N + n0 + wn + l15;
#pragma unroll
        for (int j = 0; j < 4; ++j) cp[16 * j] = acc[i][j][r];
      } else {
        u16* cp = (u16*)Cv + (size_t)row * N + n0 + wn + l15;
#pragma unroll
        for (int j = 0; j < 4; ++j) cp[16 * j] = f2b(acc[i][j][r]);
      }
    }
}

// ---------------------------------------------------------------------------
// 8-phase 256x256 NT GEMM (m201 template) — KV projection (grid 256, proven).
// ---------------------------------------------------------------------------
__global__ __launch_bounds__(512, 2) void gemm8(const u16* __restrict__ A,
                                                const u16* __restrict__ Bm,
                                                void* __restrict__ Cv,
                                                int M, int N, int K,
                                                const int* __restrict__ flag,
                                                int flag_mode) {
  __shared__ u16 Ash[2 * 256 * 64];
  __shared__ u16 Bsh[2 * 256 * 64];
  int tid = threadIdx.x, w = tid >> 6, lane = tid & 63;
  int quad = lane >> 4, l15 = lane & 15;
  int wr = w >> 2, wc = w & 3;
  int wm = wr * 128, wn = wc * 64;
  int m0 = blockIdx.y * 256, n0 = blockIdx.x * 256;
  int f32out = flag_mode ? is_f32(flag) : 0;
  const int NT = K >> 6;

  int srow8 = lane >> 3;
  int gch = (lane & 7) ^ srow8;
  const u16* Ag = A + (size_t)(m0 + w * 8 + srow8) * K + gch * 8;
  const u16* Bg = Bm + (size_t)(n0 + w * 8 + srow8) * K + gch * 8;
  int ldsrow = w * 8;  // wave-uniform LDS row base; lane*16B added by HW

  floatx4 acc[8][4];
#pragma unroll
  for (int i = 0; i < 8; ++i)
#pragma unroll
    for (int j = 0; j < 4; ++j) acc[i][j] = floatx4{0.f, 0.f, 0.f, 0.f};

  int ch0 = ((quad ^ (l15 & 7)) << 3);        // kk=0 chunk byte-> u16 offset
  int ch1 = (((4 + quad) ^ (l15 & 7)) << 3);  // kk=1

  auto stage = [&](int qi) {
    int tau = qi >> 2;
    int tc = tau < NT ? tau : NT - 1;  // clamp keeps vmcnt counts exact
    int hh = qi & 3;                   // 0:B0 1:B1 2:A0 3:A1
    int half = (hh & 1) * 128;
    int sbuf = (tau & 1) * (256 * 64);
    size_t kof = (size_t)tc * 64;
    if (hh < 2) {
      gl_lds16(Bg + (size_t)half * K + kof,
               (void*)(Bsh + sbuf + (half + ldsrow) * 64));
      gl_lds16(Bg + (size_t)(half + 64) * K + kof,
               (void*)(Bsh + sbuf + (half + 64 + ldsrow) * 64));
    } else {
      gl_lds16(Ag + (size_t)half * K + kof,
               (void*)(Ash + sbuf + (half + ldsrow) * 64));
      gl_lds16(Ag + (size_t)(half + 64) * K + kof,
               (void*)(Ash + sbuf + (half + 64 + ldsrow) * 64));
    }
  };

  // Prologue: tile0 fully + 3 half-tiles of tile1 -> 3 half-tiles in flight.
  stage(0); stage(1); stage(2); stage(3);
  __asm__ volatile("s_waitcnt vmcnt(4)" ::: "memory");
  stage(4); stage(5); stage(6);
  __asm__ volatile("s_waitcnt vmcnt(6)" ::: "memory");
  __builtin_amdgcn_s_barrier();

  for (int t = 0; t < NT; ++t) {
    u16* As = Ash + (t & 1) * (256 * 64);
    u16* Bs = Bsh + (t & 1) * (256 * 64);
    if (t) {
      __asm__ volatile("s_waitcnt vmcnt(6)" ::: "memory");
      __builtin_amdgcn_s_barrier();
    }
    int qb = 7 + 4 * t;
    short8 bf[8], af0[8], af1[8];

    // ---- P0: read af0-kk0 + bf-kk0 (8 reads); MFMA mh0 x kk0 (16) ----
#pragma unroll
    for (int j = 0; j < 4; ++j) {
      int n = wn + 16 * j + l15;
      bf[2 * j] = *(const short8*)(Bs + n * 64 + ch0);
    }
#pragma unroll
    for (int i = 0; i < 4; ++i) {
      int m = wm + 16 * i + l15;
      af0[2 * i] = *(const short8*)(As + m * 64 + ch0);
    }
    stage(qb);
    __builtin_amdgcn_s_barrier();
    __asm__ volatile("s_waitcnt lgkmcnt(0)" ::: "memory");
    __builtin_amdgcn_sched_barrier(0);
    __builtin_amdgcn_s_setprio(1);
#pragma unroll
    for (int i = 0; i < 4; ++i)
#pragma unroll
      for (int j = 0; j < 4; ++j)
        acc[i][j] = MFMA16(af0[2 * i], bf[2 * j], acc[i][j]);
    __builtin_amdgcn_s_setprio(0);
    __builtin_amdgcn_s_barrier();

    // ---- P1: read af0-kk1 + bf-kk1 (8 reads); MFMA mh0 x kk1 (16) ----
#pragma unroll
    for (int j = 0; j < 4; ++j) {
      int n = wn + 16 * j + l15;
      bf[2 * j + 1] = *(const short8*)(Bs + n * 64 + ch1);
    }
#pragma unroll
    for (int i = 0; i < 4; ++i) {
      int m = wm + 16 * i + l15;
      af0[2 * i + 1] = *(const short8*)(As + m * 64 + ch1);
    }
    stage(qb + 1);
    __builtin_amdgcn_s_barrier();
    __asm__ volatile("s_waitcnt lgkmcnt(0)" ::: "memory");
    __builtin_amdgcn_sched_barrier(0);
    __builtin_amdgcn_s_setprio(1);
#pragma unroll
    for (int i = 0; i < 4; ++i)
#pragma unroll
      for (int j = 0; j < 4; ++j)
        acc[i][j] = MFMA16(af0[2 * i + 1], bf[2 * j + 1], acc[i][j]);
    __builtin_amdgcn_s_setprio(0);
    __builtin_amdgcn_s_barrier();

    // ---- P2: read af1-kk0 (4 reads); MFMA mh1 x kk0 (16) ----
#pragma unroll
    for (int i = 0; i < 4; ++i) {
      int m = wm + 64 + 16 * i + l15;
      af1[2 * i] = *(const short8*)(As + m * 64 + ch0);
    }
    stage(qb + 2);
    __builtin_amdgcn_s_barrier();
    __asm__ volatile("s_waitcnt lgkmcnt(0)" ::: "memory");
    __builtin_amdgcn_sched_barrier(0);
    __builtin_amdgcn_s_setprio(1);
#pragma unroll
    for (int i = 0; i < 4; ++i)
#pragma unroll
      for (int j = 0; j < 4; ++j)
        acc[4 + i][j] = MFMA16(af1[2 * i], bf[2 * j], acc[4 + i][j]);
    __builtin_amdgcn_s_setprio(0);
    __builtin_amdgcn_s_barrier();

    // ---- P3: read af1-kk1 (4 reads); MFMA mh1 x kk1 (16) ----
#pragma unroll
    for (int i = 0; i < 4; ++i) {
      int m = wm + 64 + 16 * i + l15;
      af1[2 * i + 1] = *(const short8*)(As + m * 64 + ch1);
    }
    stage(qb + 3);
    __builtin_amdgcn_s_barrier();
    __asm__ volatile("s_waitcnt lgkmcnt(0)" ::: "memory");
    __builtin_amdgcn_sched_barrier(0);
    __builtin_amdgcn_s_setprio(1);
#pragma unroll
    for (int i = 0; i < 4; ++i)
#pragma unroll
      for (int j = 0; j < 4; ++j)
        acc[4 + i][j] = MFMA16(af1[2 * i + 1], bf[2 * j + 1], acc[4 + i][j]);
    __builtin_amdgcn_s_setprio(0);
    __builtin_amdgcn_s_barrier();
  }

  // Epilogue (same C/D mapping as proven gemm_nt).
#pragma unroll
  for (int i = 0; i < 8; ++i)
#pragma unroll
    for (int r = 0; r < 4; ++r) {
      int row = m0 + wm + 16 * i + quad * 4 + r;
      if (f32out) {
        float* cp = (float*)Cv + (size_t)row * N + n0 + wn + l15;
#pragma unroll
        for (int j = 0; j < 4; ++j) cp[16 * j] = acc[i][j][r];
      } else {
        u16* cp = (u16*)Cv + (size_t)row * N + n0 + wn + l15;
#pragma unroll
        for (int j = 0; j < 4; ++j) cp[16 * j] = f2b(acc[i][j][r]);
      }
    }
}

// ---------------------------------------------------------------------------
// Flash attention v10 (proven round 10): KVBLK=128, K single-buffered, V
// dbuf, per-wave P; 512 blocks heavy-first. Unchanged this round.
// ---------------------------------------------------------------------------
__global__ __launch_bounds__(512, 1) void flash_attn(const u16* __restrict__ Q,
                                                     const u16* __restrict__ KV,
                                                     const u16* __restrict__ Vt,
                                                     u16* __restrict__ O) {
  const int S = 2048, D = 2048, KVld = 4096;
  int bh = blockIdx.x;            // 0..31
  int qt = 15 - (int)blockIdx.y;  // heavy-first dispatch
  int b = bh >> 4, h = bh & 15;
  int tid = threadIdx.x, w = tid >> 6, lane = tid & 63;
  int quad = lane >> 4, l15 = lane & 15;

  const u16* Qb = Q + (size_t)(b * S) * D + h * 128;
  const u16* Kb = KV + (size_t)(b * S) * KVld + h * 128;
  const u16* Vtb = Vt + ((size_t)(b * 2048 + h * 128)) * S;

  __shared__ u16 Ksh[128 * 128];     // single buf [krow][d], 16 chunks/row
  __shared__ u16 Vsh[2][128 * 128];  // dbuf [d][k], 16 chunks/row
  __shared__ u16 Psh[8][16 * 128];   // per-wave P [16 q][128 k]

  // K tile [128 rows][128 d]: wave w rows w*16..w*16+16, 4 instrs.
  auto stage_k = [&](int kt) {
    int kb = kt * 128;
#pragma unroll
    for (int tt = 0; tt < 4; ++tt) {
      int r0 = w * 16 + tt * 4;
      int row = r0 + quad;
      int g = (l15 & 8) | ((l15 & 7) ^ (row & 7));
      gl_lds16(Kb + (size_t)(kb + row) * KVld + g * 8, (void*)(Ksh + r0 * 128));
    }
  };
  // V^T tile [128 d][128 k]: wave w d-rows w*16..w*16+16, 4 instrs.
  auto stage_v = [&](int kt, int buf) {
    int kb = kt * 128;
#pragma unroll
    for (int tt = 0; tt < 4; ++tt) {
      int d0 = w * 16 + tt * 4;
      int d = d0 + quad;
      int g = (l15 & 8) | ((l15 & 7) ^ (d & 7));
      gl_lds16(Vtb + (size_t)d * S + kb + g * 8, (void*)(Vsh[buf] + d0 * 128));
    }
  };

  int qw = qt * 128 + w * 16;  // this wave's 16 q-rows

  short8 qf[4];
  {
    const u16* qp = Qb + (size_t)(qw + l15) * D + quad * 8;
#pragma unroll
    for (int kk = 0; kk < 4; ++kk) qf[kk] = *(const short8*)(qp + kk * 32);
  }

  floatx4 o[8];
#pragma unroll
  for (int t = 0; t < 8; ++t) o[t] = floatx4{0.f, 0.f, 0.f, 0.f};
  float mrow[4], lrow[4];
#pragma unroll
  for (int r = 0; r < 4; ++r) { mrow[r] = -1e30f; lrow[r] = 0.f; }

  int nk = qt + 1;  // 128-wide k-tiles
  stage_k(0);
  stage_v(0, 0);
  __syncthreads();

  for (int kt = 0; kt < nk; ++kt) {
    int kb = kt * 128;
    int cur = kt & 1;

    // --- QK^T: 8 nf x 4 kk = 32 MFMA (reads Ksh) ---
    floatx4 sc[8];
#pragma unroll
    for (int nf = 0; nf < 8; ++nf) sc[nf] = floatx4{0.f, 0.f, 0.f, 0.f};
#pragma unroll
    for (int kk = 0; kk < 4; ++kk) {
      int c = kk * 4 + quad;
#pragma unroll
      for (int nf = 0; nf < 8; ++nf) {
        int n = nf * 16 + l15;
        int pc = (c & 8) | ((c & 7) ^ (n & 7));
        short8 kf = *(const short8*)(Ksh + n * 128 + pc * 8);
        sc[nf] = MFMA16(qf[kk], kf, sc[nf]);
      }
    }
    // #1: all waves' K reads complete
    __syncthreads();
    // prefetch next tile: K into the (now unread) single buffer, V into buf^1
    if (kt + 1 < nk) {
      stage_k(kt + 1);
      stage_v(kt + 1, cur ^ 1);
    }

    // --- online softmax (1/sqrt(dh) pre-folded into Q) ---
    bool masked = (kb + 127 > qw);
    floatx4 alv;
#pragma unroll
    for (int r = 0; r < 4; ++r) {
      int qg = qw + quad * 4 + r;
      float p[8];
#pragma unroll
      for (int g = 0; g < 8; ++g) {
        float vg = sc[g][r];
        if (masked) vg = (kb + 16 * g + l15 <= qg) ? vg : -1e30f;
        p[g] = vg;
      }
      float mx = fmaxf(fmaxf(fmaxf(p[0], p[1]), fmaxf(p[2], p[3])),
                       fmaxf(fmaxf(p[4], p[5]), fmaxf(p[6], p[7])));
      mx = max16(mx);
      float mn = fmaxf(mrow[r], mx);
      float al = __expf(mrow[r] - mn);
      mrow[r] = mn;
      float rs = 0.f;
#pragma unroll
      for (int g = 0; g < 8; ++g) {
        p[g] = __expf(p[g] - mn);
        rs += p[g];
      }
      rs = sum16(rs);
      lrow[r] = lrow[r] * al + rs;
      alv[r] = al;
      int m_ = quad * 4 + r;
      int sw = (m_ & 3) ^ ((m_ >> 2) << 1);
      int cb = l15 >> 3, e = l15 & 7;
      u16* pr = Psh[w] + m_ * 128;
#pragma unroll
      for (int g = 0; g < 8; ++g)
        pr[(((2 * g + cb) ^ sw) << 3) + e] = f2b_rn(p[g]);
    }
    // defer-rescale: al==1.0 exactly when the running max didn't grow.
    if (__any((alv[0] != 1.f) || (alv[1] != 1.f) ||
              (alv[2] != 1.f) || (alv[3] != 1.f))) {
#pragma unroll
      for (int t = 0; t < 8; ++t) o[t] *= alv;
    }
    __asm__ volatile("s_waitcnt lgkmcnt(0)" ::: "memory");

    // --- PV: 8 d x 4 ksteps = 32 MFMA (reads Vsh[cur] + Psh[w]) ---
    int psw = (l15 & 3) ^ ((l15 >> 2) << 1);
#pragma unroll
    for (int ks = 0; ks < 4; ++ks) {
      int c = ks * 4 + quad;
      short8 pf = *(const short8*)(Psh[w] + l15 * 128 + ((c ^ psw) << 3));
#pragma unroll
      for (int t = 0; t < 8; ++t) {
        int d = t * 16 + l15;
        int pc = (c & 8) | ((c & 7) ^ (d & 7));
        short8 vf = *(const short8*)(Vsh[cur] + d * 128 + pc * 8);
        o[t] = MFMA16(pf, vf, o[t]);
      }
    }
    // #2: drains this wave's prefetch gl_lds + joins waves.
    __syncthreads();
  }

  // epilogue
#pragma unroll
  for (int r = 0; r < 4; ++r) {
    float inv = 1.0f / lrow[r];
    int qg = qw + quad * 4 + r;
    u16* op = O + (size_t)(b * S + qg) * D + h * 128;
#pragma unroll
    for (int t = 0; t < 8; ++t) op[t * 16 + l15] = f2b(o[t][r] * inv);
  }
}

// ---------------------------------------------------------------------------
// Launch (round 11: 8 nodes, was 12). ws (u16 after 64-elem flag pad):
//   xb 8.4M | Wbuf 8.4M (wkvT -> Vt -> wo) | Qb 8.4M | KVb 16.8M
//   wq lives in KVb upper half until Q GEMM consumes it (KV GEMM then
//   overwrites). AO aliases xb. Total ~84 MB, unchanged.
// ---------------------------------------------------------------------------
extern "C" void kernel_launch(void* const* d_in, const int* in_sizes, int n_in,
                              void* d_out, int out_size, void* d_ws, size_t ws_size,
                              hipStream_t stream) {
  const void* x = d_in[0];
  const void* wq = d_in[1];
  const void* wkv = d_in[2];
  const void* wo = d_in[3];

  int* flag = (int*)d_ws;  // 32 ints (128 B = the 64-u16 pad)
  u16* xb = (u16*)d_ws + 64;
  u16* Wbuf = xb + (size_t)8388608;
  u16* Qb = Wbuf + (size_t)8388608;
  u16* KVb = Qb + (size_t)8388608;
  u16* wqb = KVb + (size_t)8388608;  // scratch in KVb upper half
  u16* AO = xb;                      // x dead after KV projection

  detect_f32<<<32, 256, 0, stream>>>((const u16*)x, flag);
  prep_fused<<<14336, 256, 0, stream>>>(x, wq, wkv, xb, wqb, Wbuf, flag);
  gemm_nt<<<dim3(16, 32), 256, 0, stream>>>(xb, wqb, Qb, 4096, 2048, 2048, flag, 0);
  gemm8<<<dim3(16, 16), 512, 0, stream>>>(xb, Wbuf, KVb, 4096, 4096, 2048, flag, 0);
  mid_fused<<<24576, 256, 0, stream>>>(KVb, Wbuf, Qb);  // Wbuf := Vt
  flash_attn<<<dim3(32, 16), 512, 0, stream>>>(Qb, KVb, Wbuf, AO);
  convert_in8<<<2048, 256, 0, stream>>>(wo, Wbuf, 524288, flag);
  gemm_nt<<<dim3(16, 32), 256, 0, stream>>>(AO, Wbuf, d_out, 4096, 2048, 2048, flag, 1);
}